// Round 2
// baseline (1355.635 us; speedup 1.0000x reference)
//
#include <hip/hip_runtime.h>
#include <hip/hip_bf16.h>

// Problem constants (STCN read_memory)
#define CKDIM 64
#define THW   12960     // 8*30*54
#define HWDIM 1620      // 30*54
#define NOBJ  8
#define CVAL  512
#define NB    4
#define NSTEP 405       // THW / 32
#define NJT   13        // ceil(1620/128)

using bf16x8 = __attribute__((ext_vector_type(8))) short;
using f32x4  = __attribute__((ext_vector_type(4))) float;

// round-to-nearest-even f32 -> bf16
__device__ __forceinline__ unsigned short bf_rne(float x) {
    unsigned u = __float_as_uint(x);
    u += 0x7FFFu + ((u >> 16) & 1u);
    return (unsigned short)(u >> 16);
}
__device__ __forceinline__ float bf_up(unsigned short h) {
    return __uint_as_float(((unsigned)h) << 16);
}
// pack two floats -> u32 of 2 bf16 (RNE), low short = lo
__device__ __forceinline__ unsigned pk_bf(float lo, float hi) {
    return (unsigned)bf_rne(lo) | ((unsigned)bf_rne(hi) << 16);
}

// ksq8[b][t] = (sum_c k[b,c,t]^2) / 8   (f32-exact, matches reference a_sq)
__global__ void stcn_ksq_kernel(const float* __restrict__ mk, float* __restrict__ ksq8) {
    int t = blockIdx.x * 256 + threadIdx.x;
    if (t >= THW) return;
    int b = blockIdx.y;
    const float* p = mk + (size_t)b * CKDIM * THW + t;
    float s = 0.f;
#pragma unroll
    for (int c = 0; c < CKDIM; ++c) { float v = p[(size_t)c * THW]; s = fmaf(v, v, s); }
    ksq8[b * THW + t] = s * 0.125f;
}

// MODE 0: softmax stats (m,l partials per K-chunk).  MODE 1: fused P*V with atomicAdd.
// Block: 512 threads = 8 waves. j-tile = 128. t-step = 32.
// Logits via bf16x3 split (hi+lo) MFMA -> f32-accurate, bit-identical across modes.
template <int MODE>
__global__ __launch_bounds__(512)
void stcn_aff_kernel(const float* __restrict__ mk, const float* __restrict__ qk,
                     const float* __restrict__ ksq8,
                     float* __restrict__ mpart, float* __restrict__ lpart,
                     const float* __restrict__ mv, const int* __restrict__ bmap,
                     float* __restrict__ out)
{
    // padded LDS rows (144B / 112B) -> benign 2-way bank aliasing
    __shared__ unsigned short Qt[2][128][72];   // [hi/lo][j][c]
    __shared__ unsigned short Kt[2][32][72];    // [hi/lo][t][c]
    __shared__ float k8t[32];
    __shared__ unsigned short Pt[128][56];
    __shared__ float mjs[128], iljs[128];

    const int tid  = threadIdx.x;
    const int w    = tid >> 6;        // wave 0..7
    const int lane = tid & 63;
    const int g    = lane >> 4;       // lane quad group 0..3
    const int lr   = lane & 15;

    int b, n = 0, jt, kc, cb = 0;
    if (MODE == 0) { b = blockIdx.y; jt = blockIdx.x >> 2; kc = blockIdx.x & 3; }
    else {
        n = blockIdx.y; jt = blockIdx.x >> 2; kc = (blockIdx.x >> 1) & 1; cb = blockIdx.x & 1;
        b = bmap[n];
    }
    const int jbase = jt * 128;

    // ---- stage Q tile [128 j][64 c], split hi/lo bf16, transposed to [j][c] ----
#pragma unroll
    for (int r = 0; r < 16; ++r) {
        int idx = tid + 512 * r;          // 8192 elements
        int c = idx >> 7, j = idx & 127;  // consecutive tid -> consecutive j (coalesced)
        int jg = jbase + j;
        float q = (jg < HWDIM) ? qk[((size_t)b * CKDIM + c) * HWDIM + jg] : 0.f;
        unsigned short h = bf_rne(q);
        Qt[0][j][c] = h;
        Qt[1][j][c] = bf_rne(q - bf_up(h));
    }

    float m_run = -1e30f, l_run = 0.f;   // stats mode accumulators
    float mv_j = 0.f, il_j = 0.f;

    if (MODE == 1) {
        // merge the 4 chunk-stats for this block's 128 columns
        if (tid < 128) {
            int jg = jbase + tid;
            float m = 0.f, l = 0.f;
            if (jg < HWDIM) {
                m = -1e30f;
#pragma unroll
                for (int c = 0; c < 4; ++c) {
                    float mc = mpart[(b * 4 + c) * HWDIM + jg];
                    float lc = lpart[(b * 4 + c) * HWDIM + jg];
                    float mn = fmaxf(m, mc);
                    l = l * __expf(m - mn) + lc * __expf(mc - mn);
                    m = mn;
                }
            }
            mjs[tid]  = m;
            iljs[tid] = (l > 0.f) ? 1.f / l : 0.f;   // padded cols: m=0, il=0 -> P=0, no NaN
        }
    }
    __syncthreads();

    if (MODE == 1) { mv_j = mjs[w * 16 + lr]; il_j = iljs[w * 16 + lr]; }

    int s0, s1;
    if (MODE == 0) { s0 = (NSTEP * kc) / 4; s1 = (NSTEP * (kc + 1)) / 4; }
    else           { s0 = (NSTEP * kc) / 2; s1 = (NSTEP * (kc + 1)) / 2; }

    f32x4 zz = {0.f, 0.f, 0.f, 0.f};
    f32x4 acc[4][4];
    if (MODE == 1)
#pragma unroll
        for (int i = 0; i < 4; ++i)
#pragma unroll
            for (int j = 0; j < 4; ++j) acc[i][j] = zz;

    const int wc = w >> 1, wj = w & 1;   // PV wave grid: 4 c-waves x 2 j-waves
    const float* vbase = (MODE == 1) ? (mv + ((size_t)n * CVAL + (size_t)(cb * 256 + wc * 64)) * THW)
                                     : (const float*)nullptr;

    for (int st = s0; st < s1; ++st) {
        const int t0 = st * 32;
        __syncthreads();   // B1: protect Kt/Pt vs previous iteration readers

        // ---- stage K tile [32 t][64 c], split hi/lo bf16, transposed ----
#pragma unroll
        for (int r = 0; r < 4; ++r) {
            int idx = tid + 512 * r;          // 2048 elements
            int c = idx >> 5, tt = idx & 31;  // consecutive tid -> consecutive t (coalesced)
            float kv = mk[((size_t)b * CKDIM + c) * THW + t0 + tt];
            unsigned short h = bf_rne(kv);
            Kt[0][tt][c] = h;
            Kt[1][tt][c] = bf_rne(kv - bf_up(h));
        }
        if (tid < 32) k8t[tid] = ksq8[b * THW + t0 + tid];

        // ---- issue V loads early (A-fragment layout: c = lr row, t = 8g..8g+7) ----
        float4 va[4][2];
        if (MODE == 1) {
#pragma unroll
            for (int cf = 0; cf < 4; ++cf) {
                const float4* vp = (const float4*)(vbase + (size_t)(cf * 16 + lr) * THW + t0 + 8 * g);
                va[cf][0] = vp[0];
                va[cf][1] = vp[1];
            }
        }
        __syncthreads();   // B2: Kt ready

        // ---- S tile: wave computes [32 t][16 j]; A=K[t,c], B=Q[c,j]
        //      ab = Khi*Qhi + Khi*Qlo + Klo*Qhi  (f32-accurate logits) ----
        f32x4 ab0 = zz, ab1 = zz;
#pragma unroll
        for (int s = 0; s < 2; ++s) {
            bf16x8 bqh = *(const bf16x8*)&Qt[0][w * 16 + lr][32 * s + 8 * g];
            bf16x8 bql = *(const bf16x8*)&Qt[1][w * 16 + lr][32 * s + 8 * g];
            bf16x8 a0h = *(const bf16x8*)&Kt[0][lr][32 * s + 8 * g];
            bf16x8 a0l = *(const bf16x8*)&Kt[1][lr][32 * s + 8 * g];
            bf16x8 a1h = *(const bf16x8*)&Kt[0][16 + lr][32 * s + 8 * g];
            bf16x8 a1l = *(const bf16x8*)&Kt[1][16 + lr][32 * s + 8 * g];
            ab0 = __builtin_amdgcn_mfma_f32_16x16x32_bf16(a0h, bqh, ab0, 0, 0, 0);
            ab0 = __builtin_amdgcn_mfma_f32_16x16x32_bf16(a0h, bql, ab0, 0, 0, 0);
            ab0 = __builtin_amdgcn_mfma_f32_16x16x32_bf16(a0l, bqh, ab0, 0, 0, 0);
            ab1 = __builtin_amdgcn_mfma_f32_16x16x32_bf16(a1h, bqh, ab1, 0, 0, 0);
            ab1 = __builtin_amdgcn_mfma_f32_16x16x32_bf16(a1h, bql, ab1, 0, 0, 0);
            ab1 = __builtin_amdgcn_mfma_f32_16x16x32_bf16(a1l, bqh, ab1, 0, 0, 0);
        }
        // D layout: col(j-off)=lr, row(t-local)=4g+r (+16 for ab1)

        if (MODE == 0) {
#pragma unroll
            for (int r = 0; r < 4; ++r) {
                float L0 = fmaf(ab0[r], 0.25f, -k8t[4 * g + r]);
                float mn = fmaxf(m_run, L0);
                l_run = l_run * __expf(m_run - mn) + __expf(L0 - mn);
                m_run = mn;
                float L1 = fmaf(ab1[r], 0.25f, -k8t[16 + 4 * g + r]);
                mn = fmaxf(m_run, L1);
                l_run = l_run * __expf(m_run - mn) + __expf(L1 - mn);
                m_run = mn;
            }
        } else {
            float p0[4], p1[4];
#pragma unroll
            for (int r = 0; r < 4; ++r) {
                p0[r] = __expf(fmaf(ab0[r], 0.25f, -k8t[4 * g + r]) - mv_j) * il_j;
                p1[r] = __expf(fmaf(ab1[r], 0.25f, -k8t[16 + 4 * g + r]) - mv_j) * il_j;
            }
            int jl = w * 16 + lr;
            *(unsigned*)&Pt[jl][4 * g]          = pk_bf(p0[0], p0[1]);
            *(unsigned*)&Pt[jl][4 * g + 2]      = pk_bf(p0[2], p0[3]);
            *(unsigned*)&Pt[jl][16 + 4 * g]     = pk_bf(p1[0], p1[1]);
            *(unsigned*)&Pt[jl][16 + 4 * g + 2] = pk_bf(p1[2], p1[3]);
            __syncthreads();   // B3: Pt ready

            // ---- PV: O[c,j] += V[c,t] * P[t,j]; A=V frag, B=P frag ----
            bf16x8 bp[4];
#pragma unroll
            for (int jf = 0; jf < 4; ++jf)
                bp[jf] = *(const bf16x8*)&Pt[wj * 64 + jf * 16 + lr][8 * g];
#pragma unroll
            for (int cf = 0; cf < 4; ++cf) {
                union { unsigned u[4]; bf16x8 v; } av;
                av.u[0] = pk_bf(va[cf][0].x, va[cf][0].y);
                av.u[1] = pk_bf(va[cf][0].z, va[cf][0].w);
                av.u[2] = pk_bf(va[cf][1].x, va[cf][1].y);
                av.u[3] = pk_bf(va[cf][1].z, va[cf][1].w);
#pragma unroll
                for (int jf = 0; jf < 4; ++jf)
                    acc[cf][jf] = __builtin_amdgcn_mfma_f32_16x16x32_bf16(av.v, bp[jf], acc[cf][jf], 0, 0, 0);
            }
        }
    }

    if (MODE == 0) {
        // combine lanes {lr, lr+16, lr+32, lr+48} (same j column, different t rows)
#pragma unroll
        for (int off = 16; off < 64; off <<= 1) {
            float mo = __shfl_xor(m_run, off, 64);
            float lo = __shfl_xor(l_run, off, 64);
            float mn = fmaxf(m_run, mo);
            l_run = l_run * __expf(m_run - mn) + lo * __expf(mo - mn);
            m_run = mn;
        }
        int jg = jbase + w * 16 + lr;
        if (g == 0 && jg < HWDIM) {
            mpart[(b * 4 + kc) * HWDIM + jg] = m_run;
            lpart[(b * 4 + kc) * HWDIM + jg] = l_run;
        }
    } else {
#pragma unroll
        for (int cf = 0; cf < 4; ++cf) {
#pragma unroll
            for (int jf = 0; jf < 4; ++jf) {
                int jg = jbase + wj * 64 + jf * 16 + lr;
                if (jg < HWDIM) {
                    int c = cb * 256 + wc * 64 + cf * 16 + 4 * g;
                    float* op = out + ((size_t)n * CVAL + c) * HWDIM + jg;
#pragma unroll
                    for (int r = 0; r < 4; ++r)
                        atomicAdd(op + (size_t)r * HWDIM, acc[cf][jf][r]);
                }
            }
        }
    }
}

extern "C" void kernel_launch(void* const* d_in, const int* in_sizes, int n_in,
                              void* d_out, int out_size, void* d_ws, size_t ws_size,
                              hipStream_t stream) {
    (void)in_sizes; (void)n_in; (void)ws_size;
    const float* mk   = (const float*)d_in[0];   // mem_keys   [4,64,12960]
    const float* mv   = (const float*)d_in[1];   // mem_values [8,512,12960]
    const float* qkp  = (const float*)d_in[2];   // qk         [4,64,1620]
    const int*   bmap = (const int*)d_in[3];     // broadcast_map [8]
    float* out = (float*)d_out;

    // workspace: ksq8 (4*12960) + mpart (4*4*1620) + lpart (4*4*1620)  ~ 405 KB
    float* ksq8  = (float*)d_ws;
    float* mpart = ksq8 + NB * THW;
    float* lpart = mpart + NB * 4 * HWDIM;

    hipMemsetAsync(d_out, 0, (size_t)out_size * sizeof(float), stream);

    stcn_ksq_kernel<<<dim3((THW + 255) / 256, NB), 256, 0, stream>>>(mk, ksq8);

    // stats: 13 j-tiles x 4 K-chunks x 4 batches
    stcn_aff_kernel<0><<<dim3(NJT * 4, NB), 512, 0, stream>>>(
        mk, qkp, ksq8, mpart, lpart, nullptr, nullptr, nullptr);

    // fused PV: 13 j-tiles x 2 K-chunks x 2 c-halves x 8 objects
    stcn_aff_kernel<1><<<dim3(NJT * 4, NOBJ), 512, 0, stream>>>(
        mk, qkp, ksq8, mpart, lpart, mv, bmap, out);
}

// Round 3
// 697.701 us; speedup vs baseline: 1.9430x; 1.9430x over previous
//
#include <hip/hip_runtime.h>
#include <hip/hip_bf16.h>

// STCN read_memory: affinity softmax over THW + value readout, flash-style.
#define CKDIM 64
#define THW   12960     // 8*30*54
#define HWDIM 1620      // 30*54
#define NOBJ  8
#define CVAL  512
#define NB    4
#define NSTEP 405       // THW / 32
#define NJT   13        // ceil(1620/128)
#define S2F   0.3606737602222409f   // 0.25 * log2(e)  (logits kept in log2 domain)

using bf16x8 = __attribute__((ext_vector_type(8))) short;
using f32x4  = __attribute__((ext_vector_type(4))) float;

// packed f32x2 -> bf16x2 (RNE), low short = lo
__device__ __forceinline__ unsigned cvtpk(float lo, float hi) {
    unsigned r;
    asm("v_cvt_pk_bf16_f32 %0, %1, %2" : "=v"(r) : "v"(lo), "v"(hi));
    return r;
}
__device__ __forceinline__ float fexp2(float x) {
#if __has_builtin(__builtin_amdgcn_exp2f)
    return __builtin_amdgcn_exp2f(x);
#else
    return __expf(x * 0.69314718055994531f);
#endif
}

// k8l[b][t] = (sum_c k^2)/8 * log2(e)
__global__ void stcn_ksq_kernel(const float* __restrict__ mk, float* __restrict__ k8l) {
    int t = blockIdx.x * 256 + threadIdx.x;
    if (t >= THW) return;
    int b = blockIdx.y;
    const float* p = mk + (size_t)b * CKDIM * THW + t;
    float s = 0.f;
#pragma unroll
    for (int c = 0; c < CKDIM; ++c) { float v = p[(size_t)c * THW]; s = fmaf(v, v, s); }
    k8l[b * THW + t] = s * (0.125f * 1.44269504088896341f);
}

// V f32 -> bf16 (RNE), 8 elems/thread
__global__ void stcn_vcvt_kernel(const float* __restrict__ mv, unsigned short* __restrict__ mvb) {
    size_t i = ((size_t)blockIdx.x * 256 + threadIdx.x) * 8;
    if (i >= (size_t)NOBJ * CVAL * THW) return;
    float4 v0 = *(const float4*)(mv + i);
    float4 v1 = *(const float4*)(mv + i + 4);
    uint4 o;
    o.x = cvtpk(v0.x, v0.y); o.y = cvtpk(v0.z, v0.w);
    o.z = cvtpk(v1.x, v1.y); o.w = cvtpk(v1.z, v1.w);
    *(uint4*)(mvb + i) = o;
}

// MODE 0: softmax stats (log2-domain m,l partials per K-chunk).
// MODE 1: fused P*V with atomicAdd. VB16: V pre-converted to bf16 in ws.
// 512 thr = 8 waves; j-tile 128; t-step 32; K dbuf; 2 barriers/step (MODE1).
template <int MODE, bool VB16>
__global__ __launch_bounds__(512)
void stcn_aff_kernel(const float* __restrict__ mk, const float* __restrict__ qk,
                     const float* __restrict__ k8l,
                     float* __restrict__ mpart, float* __restrict__ lpart,
                     const float* __restrict__ mv, const unsigned short* __restrict__ mvb,
                     const int* __restrict__ bmap, float* __restrict__ out)
{
    // LDS (steady):  Kt[2][32][72]u16 @0 (9216) | k8t[2][32]f32 @9216 (256)
    //                Pt[128][56]u16 @9472 (14336) | Vt[256][40]u16 @23808 (20480)
    //                mjs[128] @44288 | iljs[128] @44800
    // transient:     Qt[2][128][72]u16 @0 (36864) — dead after prologue
    constexpr int SMEM_BYTES = (MODE == 0) ? 36864 : 45312;
    __shared__ __align__(16) unsigned char smem[SMEM_BYTES];
    unsigned short* KtP   = (unsigned short*)smem;
    float*          k8tP  = (float*)(smem + 9216);
    unsigned short* PtP   = (unsigned short*)(smem + 9472);
    unsigned short* VtP   = (unsigned short*)(smem + 23808);
    float*          mjsP  = (float*)(smem + 44288);
    float*          iljsP = (float*)(smem + 44800);
    unsigned short* QtP   = (unsigned short*)smem;

    const int tid  = threadIdx.x;
    const int w    = tid >> 6;
    const int lane = tid & 63;
    const int g    = lane >> 4;
    const int lr   = lane & 15;

    int b, n = 0, jt, kc, cb = 0;
    if (MODE == 0) { b = blockIdx.y; jt = blockIdx.x >> 2; kc = blockIdx.x & 3; }
    else {
        n = blockIdx.y; jt = blockIdx.x >> 2; kc = (blockIdx.x >> 1) & 1; cb = blockIdx.x & 1;
        b = bmap[n];
    }
    const int jbase = jt * 128;
    const int cbase = cb * 256;

    // ---- prologue: Q tile -> LDS (hi/lo planes, paired-c dword writes) ----
#pragma unroll
    for (int it = 0; it < 8; ++it) {
        int idx = tid + 512 * it;             // 4096 (j, c-pair) items
        int j = idx & 127, cp = idx >> 7;
        int jg = jbase + j;
        float q0 = 0.f, q1 = 0.f;
        if (jg < HWDIM) {
            const float* qp = qk + ((size_t)b * CKDIM + 2 * cp) * HWDIM + jg;
            q0 = qp[0]; q1 = qp[HWDIM];
        }
        unsigned wh = cvtpk(q0, q1);
        float r0 = q0 - __uint_as_float(wh << 16);
        float r1 = q1 - __uint_as_float(wh & 0xFFFF0000u);
        *(unsigned*)&QtP[(0 * 128 + j) * 72 + 2 * cp] = wh;
        *(unsigned*)&QtP[(1 * 128 + j) * 72 + 2 * cp] = cvtpk(r0, r1);
    }
    __syncthreads();
    bf16x8 bqh[2], bql[2];                    // Q fragments live in registers
#pragma unroll
    for (int s = 0; s < 2; ++s) {
        bqh[s] = *(const bf16x8*)&QtP[(0 * 128 + w * 16 + lr) * 72 + 32 * s + 8 * g];
        bql[s] = *(const bf16x8*)&QtP[(1 * 128 + w * 16 + lr) * 72 + 32 * s + 8 * g];
    }
    __syncthreads();   // Qt dead; smem reusable

    auto stageK_loads = [&](int st, float2* kv) {
#pragma unroll
        for (int it = 0; it < 2; ++it) {
            int idx = tid + 512 * it;
            int tt = idx & 31, cp = idx >> 5;
            const float* kp = mk + ((size_t)b * CKDIM + 2 * cp) * THW + st * 32 + tt;
            kv[it].x = kp[0];
            kv[it].y = kp[THW];
        }
    };
    auto stageK_write = [&](int buf, const float2* kv) {
#pragma unroll
        for (int it = 0; it < 2; ++it) {
            int idx = tid + 512 * it;
            int tt = idx & 31, cp = idx >> 5;
            *(unsigned*)&KtP[(buf * 32 + tt) * 72 + 2 * cp] = cvtpk(kv[it].x, kv[it].y);
        }
    };

    int s0, s1;
    if (MODE == 0) { s0 = (NSTEP * kc) / 4; s1 = (NSTEP * (kc + 1)) / 4; }
    else           { s0 = (NSTEP * kc) / 2; s1 = (NSTEP * (kc + 1)) / 2; }

    if (MODE == 1 && tid < 128) {             // merge chunk stats (log2 domain)
        int jg = jbase + tid;
        float m = 0.f, l = 0.f;
        if (jg < HWDIM) {
            m = -1e30f;
#pragma unroll
            for (int c = 0; c < 4; ++c) {
                float mc = mpart[(b * 4 + c) * HWDIM + jg];
                float lc = lpart[(b * 4 + c) * HWDIM + jg];
                float mn = fmaxf(m, mc);
                l = l * fexp2(m - mn) + lc * fexp2(mc - mn);
                m = mn;
            }
        }
        mjsP[tid]  = m;
        iljsP[tid] = (l > 0.f) ? 1.f / l : 0.f;
    }
    {   // stage first K tile into buf 0
        float2 kv[2];
        stageK_loads(s0, kv);
        stageK_write(0, kv);
        if (tid < 32) k8tP[tid] = k8l[b * THW + s0 * 32 + tid];
    }
    __syncthreads();

    float mv_j = 0.f, il_j = 0.f;
    if (MODE == 1) { mv_j = mjsP[w * 16 + lr]; il_j = iljsP[w * 16 + lr]; }

    float m_run = -1e30f, l_run = 0.f;
    f32x4 zz = {0.f, 0.f, 0.f, 0.f};
    f32x4 acc[4][4];
    if (MODE == 1)
#pragma unroll
        for (int i = 0; i < 4; ++i)
#pragma unroll
            for (int j = 0; j < 4; ++j) acc[i][j] = zz;

    const int wc = w >> 1, wj = w & 1;        // PV wave grid: 4 c-waves x 2 j-waves
    const int vc = tid >> 1, vth = tid & 1;   // V staging: 2 threads/row, 16 t each

    int cur = 0;
    for (int st = s0; st < s1; ++st) {
        const int t0 = st * 32;
        const bool nxt = (st + 1 < s1);

        // --- issue V loads early (T14: consumed after barrier B) ---
        uint4 vw0 = {0,0,0,0}, vw1 = {0,0,0,0};
        if (MODE == 1) {
            if (VB16) {
                const unsigned short* vp = mvb + ((size_t)n * CVAL + cbase + vc) * THW + t0 + vth * 16;
                vw0 = *(const uint4*)vp;
                vw1 = *(const uint4*)(vp + 8);
            } else {
                const float* vp = mv + ((size_t)n * CVAL + cbase + vc) * THW + t0 + vth * 16;
                float4 f0 = *(const float4*)vp;
                float4 f1 = *(const float4*)(vp + 4);
                float4 f2 = *(const float4*)(vp + 8);
                float4 f3 = *(const float4*)(vp + 12);
                vw0 = make_uint4(cvtpk(f0.x,f0.y), cvtpk(f0.z,f0.w), cvtpk(f1.x,f1.y), cvtpk(f1.z,f1.w));
                vw1 = make_uint4(cvtpk(f2.x,f2.y), cvtpk(f2.z,f2.w), cvtpk(f3.x,f3.y), cvtpk(f3.z,f3.w));
            }
        }
        // --- issue next-K loads ---
        float2 kv[2];
        float k8next = 0.f;
        if (nxt) {
            stageK_loads(st + 1, kv);
            if (tid < 32) k8next = k8l[b * THW + (st + 1) * 32 + tid];
        }
        // --- S fragments from Kt[cur] ---
        bf16x8 ak0[2], ak1[2];
#pragma unroll
        for (int s = 0; s < 2; ++s) {
            ak0[s] = *(const bf16x8*)&KtP[(cur * 32 + lr) * 72 + 32 * s + 8 * g];
            ak1[s] = *(const bf16x8*)&KtP[(cur * 32 + 16 + lr) * 72 + 32 * s + 8 * g];
        }
        f32x4 k80 = *(const f32x4*)&k8tP[cur * 32 + 4 * g];
        f32x4 k81 = *(const f32x4*)&k8tP[cur * 32 + 16 + 4 * g];
        // --- S: ab = K~ * (Qhi + Qlo), identical in both modes ---
        f32x4 ab0 = zz, ab1 = zz;
#pragma unroll
        for (int s = 0; s < 2; ++s) {
            ab0 = __builtin_amdgcn_mfma_f32_16x16x32_bf16(ak0[s], bqh[s], ab0, 0, 0, 0);
            ab0 = __builtin_amdgcn_mfma_f32_16x16x32_bf16(ak0[s], bql[s], ab0, 0, 0, 0);
            ab1 = __builtin_amdgcn_mfma_f32_16x16x32_bf16(ak1[s], bqh[s], ab1, 0, 0, 0);
            ab1 = __builtin_amdgcn_mfma_f32_16x16x32_bf16(ak1[s], bql[s], ab1, 0, 0, 0);
        }
        // --- write next-K (latency covered by MFMAs above) ---
        if (nxt) {
            stageK_write(cur ^ 1, kv);
            if (tid < 32) k8tP[(cur ^ 1) * 32 + tid] = k8next;
        }

        if (MODE == 0) {
            float L0[4], L1[4], tmax = -1e30f;
#pragma unroll
            for (int r = 0; r < 4; ++r) {
                L0[r] = fmaf(ab0[r], S2F, -k80[r]); tmax = fmaxf(tmax, L0[r]);
                L1[r] = fmaf(ab1[r], S2F, -k81[r]); tmax = fmaxf(tmax, L1[r]);
            }
            float ps = 0.f;
#pragma unroll
            for (int r = 0; r < 4; ++r)
                ps += fexp2(L0[r] - tmax) + fexp2(L1[r] - tmax);
            float mn = fmaxf(m_run, tmax);
            l_run = l_run * fexp2(m_run - mn) + ps * fexp2(tmax - mn);
            m_run = mn;
            __syncthreads();
        } else {
            float p0[4], p1[4];
#pragma unroll
            for (int r = 0; r < 4; ++r) {
                p0[r] = fexp2(fmaf(ab0[r], S2F, -k80[r]) - mv_j) * il_j;
                p1[r] = fexp2(fmaf(ab1[r], S2F, -k81[r]) - mv_j) * il_j;
            }
            __syncthreads();   // A: prev-iter Pt/Vt readers done
            {
                int jl = w * 16 + lr;
                *(uint2*)&PtP[jl * 56 + 4 * g]      = make_uint2(cvtpk(p0[0], p0[1]), cvtpk(p0[2], p0[3]));
                *(uint2*)&PtP[jl * 56 + 16 + 4 * g] = make_uint2(cvtpk(p1[0], p1[1]), cvtpk(p1[2], p1[3]));
                *(uint4*)&VtP[vc * 40 + vth * 16]     = vw0;
                *(uint4*)&VtP[vc * 40 + vth * 16 + 8] = vw1;
            }
            __syncthreads();   // B: Pt/Vt ready
            bf16x8 bp[4];
#pragma unroll
            for (int jf = 0; jf < 4; ++jf)
                bp[jf] = *(const bf16x8*)&PtP[(wj * 64 + jf * 16 + lr) * 56 + 8 * g];
#pragma unroll
            for (int cf = 0; cf < 4; ++cf) {
                bf16x8 av = *(const bf16x8*)&VtP[(wc * 64 + cf * 16 + lr) * 40 + 8 * g];
#pragma unroll
                for (int jf = 0; jf < 4; ++jf)
                    acc[cf][jf] = __builtin_amdgcn_mfma_f32_16x16x32_bf16(av, bp[jf], acc[cf][jf], 0, 0, 0);
            }
        }
        cur ^= 1;
    }

    if (MODE == 0) {
        // combine the 4 g-groups (lanes lr, lr+16, lr+32, lr+48)
#pragma unroll
        for (int off = 16; off < 64; off <<= 1) {
            float mo = __shfl_xor(m_run, off, 64);
            float lo = __shfl_xor(l_run, off, 64);
            float mn = fmaxf(m_run, mo);
            l_run = l_run * fexp2(m_run - mn) + lo * fexp2(mo - mn);
            m_run = mn;
        }
        int jg = jbase + w * 16 + lr;
        if (g == 0 && jg < HWDIM) {
            mpart[(b * 4 + kc) * HWDIM + jg] = m_run;
            lpart[(b * 4 + kc) * HWDIM + jg] = l_run;
        }
    } else {
#pragma unroll
        for (int cf = 0; cf < 4; ++cf) {
#pragma unroll
            for (int jf = 0; jf < 4; ++jf) {
                int jg = jbase + wj * 64 + jf * 16 + lr;
                if (jg < HWDIM) {
                    int c = cbase + wc * 64 + cf * 16 + 4 * g;
                    float* op = out + ((size_t)n * CVAL + c) * HWDIM + jg;
#pragma unroll
                    for (int r = 0; r < 4; ++r)
                        atomicAdd(op + (size_t)r * HWDIM, acc[cf][jf][r]);
                }
            }
        }
    }
}

extern "C" void kernel_launch(void* const* d_in, const int* in_sizes, int n_in,
                              void* d_out, int out_size, void* d_ws, size_t ws_size,
                              hipStream_t stream) {
    (void)in_sizes; (void)n_in;
    const float* mk   = (const float*)d_in[0];   // mem_keys   [4,64,12960]
    const float* mv   = (const float*)d_in[1];   // mem_values [8,512,12960]
    const float* qkp  = (const float*)d_in[2];   // qk         [4,64,1620]
    const int*   bmap = (const int*)d_in[3];     // broadcast_map [8]
    float* out = (float*)d_out;

    float* k8l   = (float*)d_ws;                       // 4*12960
    float* mpart = k8l + NB * THW;                     // 4*4*1620
    float* lpart = mpart + NB * 4 * HWDIM;             // 4*4*1620
    unsigned short* mvb = (unsigned short*)(lpart + NB * 4 * HWDIM);
    size_t base_bytes = (size_t)(NB * THW + 2 * NB * 4 * HWDIM) * 4;
    size_t need = base_bytes + (size_t)NOBJ * CVAL * THW * 2;
    bool use_vb16 = (ws_size >= need);

    hipMemsetAsync(d_out, 0, (size_t)out_size * sizeof(float), stream);

    stcn_ksq_kernel<<<dim3((THW + 255) / 256, NB), 256, 0, stream>>>(mk, k8l);
    if (use_vb16) {
        size_t nthreads = (size_t)NOBJ * CVAL * THW / 8;
        stcn_vcvt_kernel<<<(unsigned)((nthreads + 255) / 256), 256, 0, stream>>>(mv, mvb);
    }

    stcn_aff_kernel<0, false><<<dim3(NJT * 4, NB), 512, 0, stream>>>(
        mk, qkp, k8l, mpart, lpart, nullptr, nullptr, nullptr, nullptr);

    if (use_vb16)
        stcn_aff_kernel<1, true><<<dim3(NJT * 4, NOBJ), 512, 0, stream>>>(
            mk, qkp, k8l, mpart, lpart, nullptr, mvb, bmap, out);
    else
        stcn_aff_kernel<1, false><<<dim3(NJT * 4, NOBJ), 512, 0, stream>>>(
            mk, qkp, k8l, mpart, lpart, mv, nullptr, bmap, out);
}

// Round 4
// 683.715 us; speedup vs baseline: 1.9827x; 1.0205x over previous
//
#include <hip/hip_runtime.h>
#include <hip/hip_bf16.h>

// STCN read_memory: affinity softmax over THW + value readout, flash-style.
#define CKDIM 64
#define THW   12960     // 8*30*54
#define HWDIM 1620      // 30*54
#define NOBJ  8
#define CVAL  512
#define NB    4
#define NSTEP 405       // THW / 32
#define NJT   13        // ceil(1620/128)
#define NCHS  8         // stats K-chunks
#define NCHP  4         // PV K-chunks
#define S2F   0.3606737602222409f   // 0.25 * log2(e)  (logits in log2 domain)

using bf16x8 = __attribute__((ext_vector_type(8))) short;
using f32x4  = __attribute__((ext_vector_type(4))) float;

// packed f32x2 -> bf16x2 (RNE), low short = lo
__device__ __forceinline__ unsigned cvtpk(float lo, float hi) {
    unsigned r;
    asm("v_cvt_pk_bf16_f32 %0, %1, %2" : "=v"(r) : "v"(lo), "v"(hi));
    return r;
}
__device__ __forceinline__ unsigned short bf_rne(float x) {
    unsigned u = __float_as_uint(x);
    u += 0x7FFFu + ((u >> 16) & 1u);
    return (unsigned short)(u >> 16);
}
__device__ __forceinline__ float fexp2(float x) {
#if __has_builtin(__builtin_amdgcn_exp2f)
    return __builtin_amdgcn_exp2f(x);
#else
    return __expf(x * 0.69314718055994531f);
#endif
}

// k8l[b][t] = (sum_c k^2)/8 * log2(e)
__global__ void stcn_ksq_kernel(const float* __restrict__ mk, float* __restrict__ k8l) {
    int t = blockIdx.x * 256 + threadIdx.x;
    if (t >= THW) return;
    int b = blockIdx.y;
    const float* p = mk + (size_t)b * CKDIM * THW + t;
    float s = 0.f;
#pragma unroll
    for (int c = 0; c < CKDIM; ++c) { float v = p[(size_t)c * THW]; s = fmaf(v, v, s); }
    k8l[b * THW + t] = s * (0.125f * 1.44269504088896341f);
}

// K [b][c][t] f32 -> kbt [b][t][c] bf16 (RNE), 64x64 tiles via LDS
__global__ __launch_bounds__(512)
void stcn_ktr_kernel(const float* __restrict__ mk, unsigned short* __restrict__ kbt) {
    __shared__ unsigned short L[64][72];
    const int tid = threadIdx.x, b = blockIdx.y, t0 = blockIdx.x * 64;
#pragma unroll
    for (int it = 0; it < 8; ++it) {
        int idx = tid + 512 * it;
        int tt = idx & 63, c = idx >> 6;
        int t = t0 + tt;
        float v = (t < THW) ? mk[((size_t)b * CKDIM + c) * THW + t] : 0.f;
        L[tt][c] = bf_rne(v);
    }
    __syncthreads();
    int tt = tid >> 3, cq = tid & 7;
    int t = t0 + tt;
    if (t < THW) {
        uint4 o = *(const uint4*)&L[tt][8 * cq];
        *(uint4*)(kbt + ((size_t)b * THW + t) * CKDIM + 8 * cq) = o;
    }
}

// V f32 -> bf16 (RNE), 8 elems/thread
__global__ void stcn_vcvt_kernel(const float* __restrict__ mv, unsigned short* __restrict__ mvb) {
    size_t i = ((size_t)blockIdx.x * 256 + threadIdx.x) * 8;
    if (i >= (size_t)NOBJ * CVAL * THW) return;
    float4 v0 = *(const float4*)(mv + i);
    float4 v1 = *(const float4*)(mv + i + 4);
    uint4 o;
    o.x = cvtpk(v0.x, v0.y); o.y = cvtpk(v0.z, v0.w);
    o.z = cvtpk(v1.x, v1.y); o.w = cvtpk(v1.z, v1.w);
    *(uint4*)(mvb + i) = o;
}

// MODE 0: softmax stats (log2-domain m,l partials per K-chunk, NCHS chunks).
// MODE 1: fused P*V with atomicAdd (NCHP chunks). VB16: V pre-bf16. KB16: K pre-bf16 [t][c].
// 512 thr = 8 waves; j-tile 128; t-step 32; K dbuf; 2 barriers/step (MODE1).
template <int MODE, bool VB16, bool KB16>
__global__ __launch_bounds__(512)
void stcn_aff_kernel(const float* __restrict__ mk, const unsigned short* __restrict__ kbt,
                     const float* __restrict__ qk, const float* __restrict__ k8l,
                     float* __restrict__ mpart, float* __restrict__ lpart,
                     const float* __restrict__ mv, const unsigned short* __restrict__ mvb,
                     const int* __restrict__ bmap, float* __restrict__ out)
{
    // LDS (steady):  Kt[2][32][72]u16 @0 (9216) | k8t[2][32]f32 @9216 (256)
    //                Pt[128][56]u16 @9472 (14336) | Vt[256][40]u16 @23808 (20480)
    //                mjs[128] @44288 | iljs[128] @44800
    // transient:     Qt[2][128][72]u16 @0 (36864) — dead after prologue
    constexpr int SMEM_BYTES = (MODE == 0) ? 36864 : 45312;
    __shared__ __align__(16) unsigned char smem[SMEM_BYTES];
    unsigned short* KtP   = (unsigned short*)smem;
    float*          k8tP  = (float*)(smem + 9216);
    unsigned short* PtP   = (unsigned short*)(smem + 9472);
    unsigned short* VtP   = (unsigned short*)(smem + 23808);
    float*          mjsP  = (float*)(smem + 44288);
    float*          iljsP = (float*)(smem + 44800);
    unsigned short* QtP   = (unsigned short*)smem;

    const int tid  = threadIdx.x;
    const int w    = tid >> 6;
    const int lane = tid & 63;
    const int g    = lane >> 4;
    const int lr   = lane & 15;

    int b, n = 0, jt, kc, cb = 0;
    if (MODE == 0) { b = blockIdx.y; jt = blockIdx.x >> 3; kc = blockIdx.x & 7; }
    else {
        n = blockIdx.y; jt = blockIdx.x >> 3; kc = (blockIdx.x >> 1) & 3; cb = blockIdx.x & 1;
        b = bmap[n];
    }
    const int jbase = jt * 128;
    const int cbase = cb * 256;

    // ---- prologue: Q tile -> LDS (hi/lo planes, paired-c dword writes) ----
#pragma unroll
    for (int it = 0; it < 8; ++it) {
        int idx = tid + 512 * it;             // 4096 (j, c-pair) items
        int j = idx & 127, cp = idx >> 7;
        int jg = jbase + j;
        float q0 = 0.f, q1 = 0.f;
        if (jg < HWDIM) {
            const float* qp = qk + ((size_t)b * CKDIM + 2 * cp) * HWDIM + jg;
            q0 = qp[0]; q1 = qp[HWDIM];
        }
        unsigned wh = cvtpk(q0, q1);
        float r0 = q0 - __uint_as_float(wh << 16);
        float r1 = q1 - __uint_as_float(wh & 0xFFFF0000u);
        *(unsigned*)&QtP[(0 * 128 + j) * 72 + 2 * cp] = wh;
        *(unsigned*)&QtP[(1 * 128 + j) * 72 + 2 * cp] = cvtpk(r0, r1);
    }
    __syncthreads();
    bf16x8 bqh[2], bql[2];                    // Q fragments live in registers
#pragma unroll
    for (int s = 0; s < 2; ++s) {
        bqh[s] = *(const bf16x8*)&QtP[(0 * 128 + w * 16 + lr) * 72 + 32 * s + 8 * g];
        bql[s] = *(const bf16x8*)&QtP[(1 * 128 + w * 16 + lr) * 72 + 32 * s + 8 * g];
    }
    __syncthreads();   // Qt dead; smem reusable

    auto stageK_loads = [&](int st, uint2& k16, float2* kvf) {
        if constexpr (KB16) {
            int tt = tid >> 4, cq = tid & 15;
            k16 = *(const uint2*)(kbt + ((size_t)b * THW + st * 32 + tt) * CKDIM + 4 * cq);
        } else {
#pragma unroll
            for (int it = 0; it < 2; ++it) {
                int idx = tid + 512 * it;
                int tt = idx & 31, cp = idx >> 5;
                const float* kp = mk + ((size_t)b * CKDIM + 2 * cp) * THW + st * 32 + tt;
                kvf[it].x = kp[0];
                kvf[it].y = kp[THW];
            }
        }
    };
    auto stageK_write = [&](int buf, uint2 k16, const float2* kvf) {
        if constexpr (KB16) {
            int tt = tid >> 4, cq = tid & 15;
            *(uint2*)&KtP[(buf * 32 + tt) * 72 + 4 * cq] = k16;
        } else {
#pragma unroll
            for (int it = 0; it < 2; ++it) {
                int idx = tid + 512 * it;
                int tt = idx & 31, cp = idx >> 5;
                *(unsigned*)&KtP[(buf * 32 + tt) * 72 + 2 * cp] = cvtpk(kvf[it].x, kvf[it].y);
            }
        }
    };

    int s0, s1;
    if (MODE == 0) { s0 = (NSTEP * kc) / NCHS; s1 = (NSTEP * (kc + 1)) / NCHS; }
    else           { s0 = (NSTEP * kc) / NCHP; s1 = (NSTEP * (kc + 1)) / NCHP; }

    if (MODE == 1 && tid < 128) {             // merge chunk stats (log2 domain)
        int jg = jbase + tid;
        float m = 0.f, l = 0.f;
        if (jg < HWDIM) {
            m = -1e30f;
#pragma unroll
            for (int c = 0; c < NCHS; ++c) {
                float mc = mpart[(b * NCHS + c) * HWDIM + jg];
                float lc = lpart[(b * NCHS + c) * HWDIM + jg];
                float mn = fmaxf(m, mc);
                l = l * fexp2(m - mn) + lc * fexp2(mc - mn);
                m = mn;
            }
        }
        mjsP[tid]  = m;
        iljsP[tid] = (l > 0.f) ? 1.f / l : 0.f;
    }
    {   // stage first K tile into buf 0
        uint2 k16; float2 kvf[2];
        stageK_loads(s0, k16, kvf);
        stageK_write(0, k16, kvf);
        if (tid < 32) k8tP[tid] = k8l[b * THW + s0 * 32 + tid];
    }
    __syncthreads();

    float mv_j = 0.f, il_j = 0.f;
    if (MODE == 1) { mv_j = mjsP[w * 16 + lr]; il_j = iljsP[w * 16 + lr]; }

    float m_run = -1e30f, l_run = 0.f;
    f32x4 zz = {0.f, 0.f, 0.f, 0.f};
    f32x4 acc[4][4];
    if (MODE == 1)
#pragma unroll
        for (int i = 0; i < 4; ++i)
#pragma unroll
            for (int j = 0; j < 4; ++j) acc[i][j] = zz;

    const int wc = w >> 1, wj = w & 1;        // PV wave grid: 4 c-waves x 2 j-waves
    const int vc = tid >> 1, vth = tid & 1;   // V staging: 2 threads/row, 16 t each

    int cur = 0;
    for (int st = s0; st < s1; ++st) {
        const int t0 = st * 32;
        const bool nxt = (st + 1 < s1);

        // --- issue V loads early (T14: consumed after barrier B) ---
        uint4 vw0 = {0,0,0,0}, vw1 = {0,0,0,0};
        if (MODE == 1) {
            if (VB16) {
                const unsigned short* vp = mvb + ((size_t)n * CVAL + cbase + vc) * THW + t0 + vth * 16;
                vw0 = *(const uint4*)vp;
                vw1 = *(const uint4*)(vp + 8);
            } else {
                const float* vp = mv + ((size_t)n * CVAL + cbase + vc) * THW + t0 + vth * 16;
                float4 f0 = *(const float4*)vp;
                float4 f1 = *(const float4*)(vp + 4);
                float4 f2 = *(const float4*)(vp + 8);
                float4 f3 = *(const float4*)(vp + 12);
                vw0 = make_uint4(cvtpk(f0.x,f0.y), cvtpk(f0.z,f0.w), cvtpk(f1.x,f1.y), cvtpk(f1.z,f1.w));
                vw1 = make_uint4(cvtpk(f2.x,f2.y), cvtpk(f2.z,f2.w), cvtpk(f3.x,f3.y), cvtpk(f3.z,f3.w));
            }
        }
        // --- issue next-K loads ---
        uint2 k16; float2 kvf[2];
        float k8next = 0.f;
        if (nxt) {
            stageK_loads(st + 1, k16, kvf);
            if (tid < 32) k8next = k8l[b * THW + (st + 1) * 32 + tid];
        }
        // --- S fragments from Kt[cur] ---
        bf16x8 ak0[2], ak1[2];
#pragma unroll
        for (int s = 0; s < 2; ++s) {
            ak0[s] = *(const bf16x8*)&KtP[(cur * 32 + lr) * 72 + 32 * s + 8 * g];
            ak1[s] = *(const bf16x8*)&KtP[(cur * 32 + 16 + lr) * 72 + 32 * s + 8 * g];
        }
        f32x4 k80 = *(const f32x4*)&k8tP[cur * 32 + 4 * g];
        f32x4 k81 = *(const f32x4*)&k8tP[cur * 32 + 16 + 4 * g];
        // --- S: ab = K~ * (Qhi + Qlo), identical in both modes ---
        f32x4 ab0 = zz, ab1 = zz;
#pragma unroll
        for (int s = 0; s < 2; ++s) {
            ab0 = __builtin_amdgcn_mfma_f32_16x16x32_bf16(ak0[s], bqh[s], ab0, 0, 0, 0);
            ab0 = __builtin_amdgcn_mfma_f32_16x16x32_bf16(ak0[s], bql[s], ab0, 0, 0, 0);
            ab1 = __builtin_amdgcn_mfma_f32_16x16x32_bf16(ak1[s], bqh[s], ab1, 0, 0, 0);
            ab1 = __builtin_amdgcn_mfma_f32_16x16x32_bf16(ak1[s], bql[s], ab1, 0, 0, 0);
        }
        // --- write next-K (latency covered by MFMAs above) ---
        if (nxt) {
            stageK_write(cur ^ 1, k16, kvf);
            if (tid < 32) k8tP[(cur ^ 1) * 32 + tid] = k8next;
        }

        if (MODE == 0) {
            float L0[4], L1[4], tmax = -1e30f;
#pragma unroll
            for (int r = 0; r < 4; ++r) {
                L0[r] = fmaf(ab0[r], S2F, -k80[r]); tmax = fmaxf(tmax, L0[r]);
                L1[r] = fmaf(ab1[r], S2F, -k81[r]); tmax = fmaxf(tmax, L1[r]);
            }
            float ps = 0.f;
#pragma unroll
            for (int r = 0; r < 4; ++r)
                ps += fexp2(L0[r] - tmax) + fexp2(L1[r] - tmax);
            float mn = fmaxf(m_run, tmax);
            l_run = l_run * fexp2(m_run - mn) + ps * fexp2(tmax - mn);
            m_run = mn;
            __syncthreads();
        } else {
            float p0[4], p1[4];
#pragma unroll
            for (int r = 0; r < 4; ++r) {
                p0[r] = fexp2(fmaf(ab0[r], S2F, -k80[r]) - mv_j) * il_j;
                p1[r] = fexp2(fmaf(ab1[r], S2F, -k81[r]) - mv_j) * il_j;
            }
            __syncthreads();   // A: prev-iter Pt/Vt readers done
            {
                int jl = w * 16 + lr;
                *(uint2*)&PtP[jl * 56 + 4 * g]      = make_uint2(cvtpk(p0[0], p0[1]), cvtpk(p0[2], p0[3]));
                *(uint2*)&PtP[jl * 56 + 16 + 4 * g] = make_uint2(cvtpk(p1[0], p1[1]), cvtpk(p1[2], p1[3]));
                *(uint4*)&VtP[vc * 40 + vth * 16]     = vw0;
                *(uint4*)&VtP[vc * 40 + vth * 16 + 8] = vw1;
            }
            __syncthreads();   // B: Pt/Vt ready
            bf16x8 bp[4];
#pragma unroll
            for (int jf = 0; jf < 4; ++jf)
                bp[jf] = *(const bf16x8*)&PtP[(wj * 64 + jf * 16 + lr) * 56 + 8 * g];
#pragma unroll
            for (int cf = 0; cf < 4; ++cf) {
                bf16x8 av = *(const bf16x8*)&VtP[(wc * 64 + cf * 16 + lr) * 40 + 8 * g];
#pragma unroll
                for (int jf = 0; jf < 4; ++jf)
                    acc[cf][jf] = __builtin_amdgcn_mfma_f32_16x16x32_bf16(av, bp[jf], acc[cf][jf], 0, 0, 0);
            }
        }
        cur ^= 1;
    }

    if (MODE == 0) {
        // combine the 4 g-groups (lanes lr, lr+16, lr+32, lr+48)
#pragma unroll
        for (int off = 16; off < 64; off <<= 1) {
            float mo = __shfl_xor(m_run, off, 64);
            float lo = __shfl_xor(l_run, off, 64);
            float mn = fmaxf(m_run, mo);
            l_run = l_run * fexp2(m_run - mn) + lo * fexp2(mo - mn);
            m_run = mn;
        }
        int jg = jbase + w * 16 + lr;
        if (g == 0 && jg < HWDIM) {
            mpart[(b * NCHS + kc) * HWDIM + jg] = m_run;
            lpart[(b * NCHS + kc) * HWDIM + jg] = l_run;
        }
    } else {
#pragma unroll
        for (int cf = 0; cf < 4; ++cf) {
#pragma unroll
            for (int jf = 0; jf < 4; ++jf) {
                int jg = jbase + wj * 64 + jf * 16 + lr;
                if (jg < HWDIM) {
                    int c = cbase + wc * 64 + cf * 16 + 4 * g;
                    float* op = out + ((size_t)n * CVAL + c) * HWDIM + jg;
#pragma unroll
                    for (int r = 0; r < 4; ++r)
                        atomicAdd(op + (size_t)r * HWDIM, acc[cf][jf][r]);
                }
            }
        }
    }
}

extern "C" void kernel_launch(void* const* d_in, const int* in_sizes, int n_in,
                              void* d_out, int out_size, void* d_ws, size_t ws_size,
                              hipStream_t stream) {
    (void)in_sizes; (void)n_in;
    const float* mk   = (const float*)d_in[0];   // mem_keys   [4,64,12960]
    const float* mv   = (const float*)d_in[1];   // mem_values [8,512,12960]
    const float* qkp  = (const float*)d_in[2];   // qk         [4,64,1620]
    const int*   bmap = (const int*)d_in[3];     // broadcast_map [8]
    float* out = (float*)d_out;

    float* k8l   = (float*)d_ws;                          // NB*THW f32
    float* mpart = k8l + NB * THW;                        // NB*NCHS*HWDIM f32
    float* lpart = mpart + NB * NCHS * HWDIM;             // NB*NCHS*HWDIM f32
    unsigned short* mvb = (unsigned short*)(lpart + NB * NCHS * HWDIM);  // NOBJ*CVAL*THW bf16
    unsigned short* kbt = mvb + (size_t)NOBJ * CVAL * THW;               // NB*THW*64 bf16

    size_t base_bytes = (size_t)(NB * THW + 2 * NB * NCHS * HWDIM) * 4;
    size_t need_vb  = base_bytes + (size_t)NOBJ * CVAL * THW * 2;
    size_t need_kbt = need_vb + (size_t)NB * THW * CKDIM * 2;
    bool use_vb16 = (ws_size >= need_vb);
    bool use_kbt  = (ws_size >= need_kbt);

    hipMemsetAsync(d_out, 0, (size_t)out_size * sizeof(float), stream);

    stcn_ksq_kernel<<<dim3((THW + 255) / 256, NB), 256, 0, stream>>>(mk, k8l);
    if (use_kbt)
        stcn_ktr_kernel<<<dim3((THW + 63) / 64, NB), 512, 0, stream>>>(mk, kbt);
    if (use_vb16) {
        size_t nthreads = (size_t)NOBJ * CVAL * THW / 8;
        stcn_vcvt_kernel<<<(unsigned)((nthreads + 255) / 256), 256, 0, stream>>>(mv, mvb);
    }

    // stats: 13 j-tiles x 8 K-chunks x 4 batches = 416 blocks
    if (use_kbt)
        stcn_aff_kernel<0, false, true><<<dim3(NJT * NCHS, NB), 512, 0, stream>>>(
            mk, kbt, qkp, k8l, mpart, lpart, nullptr, nullptr, nullptr, nullptr);
    else
        stcn_aff_kernel<0, false, false><<<dim3(NJT * NCHS, NB), 512, 0, stream>>>(
            mk, nullptr, qkp, k8l, mpart, lpart, nullptr, nullptr, nullptr, nullptr);

    // fused PV: 13 j-tiles x 4 K-chunks x 2 c-halves x 8 objects = 832 blocks
    dim3 g1(NJT * NCHP * 2, NOBJ);
    if (use_vb16 && use_kbt)
        stcn_aff_kernel<1, true, true><<<g1, 512, 0, stream>>>(
            mk, kbt, qkp, k8l, mpart, lpart, nullptr, mvb, bmap, out);
    else if (use_vb16)
        stcn_aff_kernel<1, true, false><<<g1, 512, 0, stream>>>(
            mk, nullptr, qkp, k8l, mpart, lpart, nullptr, mvb, bmap, out);
    else
        stcn_aff_kernel<1, false, false><<<g1, 512, 0, stream>>>(
            mk, nullptr, qkp, k8l, mpart, lpart, mv, nullptr, bmap, out);
}

// Round 5
// 571.159 us; speedup vs baseline: 2.3735x; 1.1971x over previous
//
#include <hip/hip_runtime.h>
#include <hip/hip_bf16.h>

// STCN read_memory: affinity softmax over THW + value readout.
#define CKDIM 64
#define THW   12960     // 8*30*54
#define HWDIM 1620      // 30*54
#define NOBJ  8
#define CVAL  512
#define NB    4
#define NSTEP 405       // THW / 32
#define NJT   13        // ceil(1620/128)
#define NCHS  8         // stats K-chunks
#define NCHP  4         // fallback fused-PV K-chunks
#define PCH   16        // P-write K-chunks
#define S2F   0.3606737602222409f   // 0.25 * log2(e)

using bf16x8 = __attribute__((ext_vector_type(8))) short;
using f32x4  = __attribute__((ext_vector_type(4))) float;

__device__ __forceinline__ unsigned cvtpk(float lo, float hi) {
    unsigned r;
    asm("v_cvt_pk_bf16_f32 %0, %1, %2" : "=v"(r) : "v"(lo), "v"(hi));
    return r;
}
__device__ __forceinline__ unsigned short bf_rne(float x) {
    unsigned u = __float_as_uint(x);
    u += 0x7FFFu + ((u >> 16) & 1u);
    return (unsigned short)(u >> 16);
}
__device__ __forceinline__ float fexp2(float x) {
#if __has_builtin(__builtin_amdgcn_exp2f)
    return __builtin_amdgcn_exp2f(x);
#else
    return __expf(x * 0.69314718055994531f);
#endif
}

// k8l[b][t] = (sum_c k^2)/8 * log2(e)
__global__ void stcn_ksq_kernel(const float* __restrict__ mk, float* __restrict__ k8l) {
    int t = blockIdx.x * 256 + threadIdx.x;
    if (t >= THW) return;
    int b = blockIdx.y;
    const float* p = mk + (size_t)b * CKDIM * THW + t;
    float s = 0.f;
#pragma unroll
    for (int c = 0; c < CKDIM; ++c) { float v = p[(size_t)c * THW]; s = fmaf(v, v, s); }
    k8l[b * THW + t] = s * (0.125f * 1.44269504088896341f);
}

// K [b][c][t] f32 -> kbt [b][t][c] bf16 (RNE)
__global__ __launch_bounds__(512)
void stcn_ktr_kernel(const float* __restrict__ mk, unsigned short* __restrict__ kbt) {
    __shared__ unsigned short L[64][72];
    const int tid = threadIdx.x, b = blockIdx.y, t0 = blockIdx.x * 64;
#pragma unroll
    for (int it = 0; it < 8; ++it) {
        int idx = tid + 512 * it;
        int tt = idx & 63, c = idx >> 6;
        int t = t0 + tt;
        float v = (t < THW) ? mk[((size_t)b * CKDIM + c) * THW + t] : 0.f;
        L[tt][c] = bf_rne(v);
    }
    __syncthreads();
    int tt = tid >> 3, cq = tid & 7;
    int t = t0 + tt;
    if (t < THW) {
        uint4 o = *(const uint4*)&L[tt][8 * cq];
        *(uint4*)(kbt + ((size_t)b * THW + t) * CKDIM + 8 * cq) = o;
    }
}

// V f32 -> bf16 (RNE)
__global__ void stcn_vcvt_kernel(const float* __restrict__ mv, unsigned short* __restrict__ mvb) {
    size_t i = ((size_t)blockIdx.x * 256 + threadIdx.x) * 8;
    if (i >= (size_t)NOBJ * CVAL * THW) return;
    float4 v0 = *(const float4*)(mv + i);
    float4 v1 = *(const float4*)(mv + i + 4);
    uint4 o;
    o.x = cvtpk(v0.x, v0.y); o.y = cvtpk(v0.z, v0.w);
    o.z = cvtpk(v1.x, v1.y); o.w = cvtpk(v1.z, v1.w);
    *(uint4*)(mvb + i) = o;
}

// ---------------- R4 fused kernel (stats MODE 0 for both paths; MODE 1 = fallback PV) ----------------
template <int MODE, bool VB16, bool KB16>
__global__ __launch_bounds__(512, (MODE == 1) ? 4 : 1)
void stcn_aff_kernel(const float* __restrict__ mk, const unsigned short* __restrict__ kbt,
                     const float* __restrict__ qk, const float* __restrict__ k8l,
                     float* __restrict__ mpart, float* __restrict__ lpart,
                     const float* __restrict__ mv, const unsigned short* __restrict__ mvb,
                     const int* __restrict__ bmap, float* __restrict__ out)
{
    constexpr int SMEM_BYTES = (MODE == 0) ? 36864 : 45312;
    __shared__ __align__(16) unsigned char smem[SMEM_BYTES];
    unsigned short* KtP   = (unsigned short*)smem;
    float*          k8tP  = (float*)(smem + 9216);
    unsigned short* PtP   = (unsigned short*)(smem + 9472);
    unsigned short* VtP   = (unsigned short*)(smem + 23808);
    float*          mjsP  = (float*)(smem + 44288);
    float*          iljsP = (float*)(smem + 44800);
    unsigned short* QtP   = (unsigned short*)smem;

    const int tid  = threadIdx.x;
    const int w    = tid >> 6;
    const int lane = tid & 63;
    const int g    = lane >> 4;
    const int lr   = lane & 15;

    int b, n = 0, jt, kc, cb = 0;
    if (MODE == 0) { b = blockIdx.y; jt = blockIdx.x >> 3; kc = blockIdx.x & 7; }
    else {
        n = blockIdx.y; jt = blockIdx.x >> 3; kc = (blockIdx.x >> 1) & 3; cb = blockIdx.x & 1;
        b = bmap[n];
    }
    const int jbase = jt * 128;
    const int cbase = cb * 256;

#pragma unroll
    for (int it = 0; it < 8; ++it) {
        int idx = tid + 512 * it;
        int j = idx & 127, cp = idx >> 7;
        int jg = jbase + j;
        float q0 = 0.f, q1 = 0.f;
        if (jg < HWDIM) {
            const float* qp = qk + ((size_t)b * CKDIM + 2 * cp) * HWDIM + jg;
            q0 = qp[0]; q1 = qp[HWDIM];
        }
        unsigned wh = cvtpk(q0, q1);
        float r0 = q0 - __uint_as_float(wh << 16);
        float r1 = q1 - __uint_as_float(wh & 0xFFFF0000u);
        *(unsigned*)&QtP[(0 * 128 + j) * 72 + 2 * cp] = wh;
        *(unsigned*)&QtP[(1 * 128 + j) * 72 + 2 * cp] = cvtpk(r0, r1);
    }
    __syncthreads();
    bf16x8 bqh[2], bql[2];
#pragma unroll
    for (int s = 0; s < 2; ++s) {
        bqh[s] = *(const bf16x8*)&QtP[(0 * 128 + w * 16 + lr) * 72 + 32 * s + 8 * g];
        bql[s] = *(const bf16x8*)&QtP[(1 * 128 + w * 16 + lr) * 72 + 32 * s + 8 * g];
    }
    __syncthreads();

    auto stageK_loads = [&](int st, uint2& k16, float2* kvf) {
        if constexpr (KB16) {
            int tt = tid >> 4, cq = tid & 15;
            k16 = *(const uint2*)(kbt + ((size_t)b * THW + st * 32 + tt) * CKDIM + 4 * cq);
        } else {
#pragma unroll
            for (int it = 0; it < 2; ++it) {
                int idx = tid + 512 * it;
                int tt = idx & 31, cp = idx >> 5;
                const float* kp = mk + ((size_t)b * CKDIM + 2 * cp) * THW + st * 32 + tt;
                kvf[it].x = kp[0];
                kvf[it].y = kp[THW];
            }
        }
    };
    auto stageK_write = [&](int buf, uint2 k16, const float2* kvf) {
        if constexpr (KB16) {
            int tt = tid >> 4, cq = tid & 15;
            *(uint2*)&KtP[(buf * 32 + tt) * 72 + 4 * cq] = k16;
        } else {
#pragma unroll
            for (int it = 0; it < 2; ++it) {
                int idx = tid + 512 * it;
                int tt = idx & 31, cp = idx >> 5;
                *(unsigned*)&KtP[(buf * 32 + tt) * 72 + 2 * cp] = cvtpk(kvf[it].x, kvf[it].y);
            }
        }
    };

    int s0, s1;
    if (MODE == 0) { s0 = (NSTEP * kc) / NCHS; s1 = (NSTEP * (kc + 1)) / NCHS; }
    else           { s0 = (NSTEP * kc) / NCHP; s1 = (NSTEP * (kc + 1)) / NCHP; }

    if (MODE == 1 && tid < 128) {
        int jg = jbase + tid;
        float m = 0.f, l = 0.f;
        if (jg < HWDIM) {
            m = -1e30f;
#pragma unroll
            for (int c = 0; c < NCHS; ++c) {
                float mc = mpart[(b * NCHS + c) * HWDIM + jg];
                float lc = lpart[(b * NCHS + c) * HWDIM + jg];
                float mn = fmaxf(m, mc);
                l = l * fexp2(m - mn) + lc * fexp2(mc - mn);
                m = mn;
            }
        }
        mjsP[tid]  = m;
        iljsP[tid] = (l > 0.f) ? 1.f / l : 0.f;
    }
    {
        uint2 k16; float2 kvf[2];
        stageK_loads(s0, k16, kvf);
        stageK_write(0, k16, kvf);
        if (tid < 32) k8tP[tid] = k8l[b * THW + s0 * 32 + tid];
    }
    __syncthreads();

    float mv_j = 0.f, il_j = 0.f;
    if (MODE == 1) { mv_j = mjsP[w * 16 + lr]; il_j = iljsP[w * 16 + lr]; }

    float m_run = -1e30f, l_run = 0.f;
    f32x4 zz = {0.f, 0.f, 0.f, 0.f};
    f32x4 acc[4][4];
    if (MODE == 1)
#pragma unroll
        for (int i = 0; i < 4; ++i)
#pragma unroll
            for (int j = 0; j < 4; ++j) acc[i][j] = zz;

    const int wc = w >> 1, wj = w & 1;
    const int vc = tid >> 1, vth = tid & 1;

    int cur = 0;
    for (int st = s0; st < s1; ++st) {
        const int t0 = st * 32;
        const bool nxt = (st + 1 < s1);

        uint4 vw0 = {0,0,0,0}, vw1 = {0,0,0,0};
        if (MODE == 1) {
            if (VB16) {
                const unsigned short* vp = mvb + ((size_t)n * CVAL + cbase + vc) * THW + t0 + vth * 16;
                vw0 = *(const uint4*)vp;
                vw1 = *(const uint4*)(vp + 8);
            } else {
                const float* vp = mv + ((size_t)n * CVAL + cbase + vc) * THW + t0 + vth * 16;
                float4 f0 = *(const float4*)vp;
                float4 f1 = *(const float4*)(vp + 4);
                float4 f2 = *(const float4*)(vp + 8);
                float4 f3 = *(const float4*)(vp + 12);
                vw0 = make_uint4(cvtpk(f0.x,f0.y), cvtpk(f0.z,f0.w), cvtpk(f1.x,f1.y), cvtpk(f1.z,f1.w));
                vw1 = make_uint4(cvtpk(f2.x,f2.y), cvtpk(f2.z,f2.w), cvtpk(f3.x,f3.y), cvtpk(f3.z,f3.w));
            }
        }
        uint2 k16; float2 kvf[2];
        float k8next = 0.f;
        if (nxt) {
            stageK_loads(st + 1, k16, kvf);
            if (tid < 32) k8next = k8l[b * THW + (st + 1) * 32 + tid];
        }
        bf16x8 ak0[2], ak1[2];
#pragma unroll
        for (int s = 0; s < 2; ++s) {
            ak0[s] = *(const bf16x8*)&KtP[(cur * 32 + lr) * 72 + 32 * s + 8 * g];
            ak1[s] = *(const bf16x8*)&KtP[(cur * 32 + 16 + lr) * 72 + 32 * s + 8 * g];
        }
        f32x4 k80 = *(const f32x4*)&k8tP[cur * 32 + 4 * g];
        f32x4 k81 = *(const f32x4*)&k8tP[cur * 32 + 16 + 4 * g];
        f32x4 ab0 = zz, ab1 = zz;
#pragma unroll
        for (int s = 0; s < 2; ++s) {
            ab0 = __builtin_amdgcn_mfma_f32_16x16x32_bf16(ak0[s], bqh[s], ab0, 0, 0, 0);
            ab0 = __builtin_amdgcn_mfma_f32_16x16x32_bf16(ak0[s], bql[s], ab0, 0, 0, 0);
            ab1 = __builtin_amdgcn_mfma_f32_16x16x32_bf16(ak1[s], bqh[s], ab1, 0, 0, 0);
            ab1 = __builtin_amdgcn_mfma_f32_16x16x32_bf16(ak1[s], bql[s], ab1, 0, 0, 0);
        }
        if (nxt) {
            stageK_write(cur ^ 1, k16, kvf);
            if (tid < 32) k8tP[(cur ^ 1) * 32 + tid] = k8next;
        }

        if (MODE == 0) {
            float L0[4], L1[4], tmax = -1e30f;
#pragma unroll
            for (int r = 0; r < 4; ++r) {
                L0[r] = fmaf(ab0[r], S2F, -k80[r]); tmax = fmaxf(tmax, L0[r]);
                L1[r] = fmaf(ab1[r], S2F, -k81[r]); tmax = fmaxf(tmax, L1[r]);
            }
            float ps = 0.f;
#pragma unroll
            for (int r = 0; r < 4; ++r)
                ps += fexp2(L0[r] - tmax) + fexp2(L1[r] - tmax);
            float mn = fmaxf(m_run, tmax);
            l_run = l_run * fexp2(m_run - mn) + ps * fexp2(tmax - mn);
            m_run = mn;
            __syncthreads();
        } else {
            float p0[4], p1[4];
#pragma unroll
            for (int r = 0; r < 4; ++r) {
                p0[r] = fexp2(fmaf(ab0[r], S2F, -k80[r]) - mv_j) * il_j;
                p1[r] = fexp2(fmaf(ab1[r], S2F, -k81[r]) - mv_j) * il_j;
            }
            __syncthreads();
            {
                int jl = w * 16 + lr;
                *(uint2*)&PtP[jl * 56 + 4 * g]      = make_uint2(cvtpk(p0[0], p0[1]), cvtpk(p0[2], p0[3]));
                *(uint2*)&PtP[jl * 56 + 16 + 4 * g] = make_uint2(cvtpk(p1[0], p1[1]), cvtpk(p1[2], p1[3]));
                *(uint4*)&VtP[vc * 40 + vth * 16]     = vw0;
                *(uint4*)&VtP[vc * 40 + vth * 16 + 8] = vw1;
            }
            __syncthreads();
            bf16x8 bp[4];
#pragma unroll
            for (int jf = 0; jf < 4; ++jf)
                bp[jf] = *(const bf16x8*)&PtP[(wj * 64 + jf * 16 + lr) * 56 + 8 * g];
#pragma unroll
            for (int cf = 0; cf < 4; ++cf) {
                bf16x8 av = *(const bf16x8*)&VtP[(wc * 64 + cf * 16 + lr) * 40 + 8 * g];
#pragma unroll
                for (int jf = 0; jf < 4; ++jf)
                    acc[cf][jf] = __builtin_amdgcn_mfma_f32_16x16x32_bf16(av, bp[jf], acc[cf][jf], 0, 0, 0);
            }
        }
        cur ^= 1;
    }

    if (MODE == 0) {
#pragma unroll
        for (int off = 16; off < 64; off <<= 1) {
            float mo = __shfl_xor(m_run, off, 64);
            float lo = __shfl_xor(l_run, off, 64);
            float mn = fmaxf(m_run, mo);
            l_run = l_run * fexp2(m_run - mn) + lo * fexp2(mo - mn);
            m_run = mn;
        }
        int jg = jbase + w * 16 + lr;
        if (g == 0 && jg < HWDIM) {
            mpart[(b * NCHS + kc) * HWDIM + jg] = m_run;
            lpart[(b * NCHS + kc) * HWDIM + jg] = l_run;
        }
    } else {
#pragma unroll
        for (int cf = 0; cf < 4; ++cf) {
#pragma unroll
            for (int jf = 0; jf < 4; ++jf) {
                int jg = jbase + wj * 64 + jf * 16 + lr;
                if (jg < HWDIM) {
                    int c = cbase + wc * 64 + cf * 16 + 4 * g;
                    float* op = out + ((size_t)n * CVAL + c) * HWDIM + jg;
#pragma unroll
                    for (int r = 0; r < 4; ++r)
                        atomicAdd(op + (size_t)r * HWDIM, acc[cf][jf][r]);
                }
            }
        }
    }
}

// ---------------- P-write: softmax'd P (bf16) -> Pws[bb][j][t], once per batch ----------------
__global__ __launch_bounds__(512)
void stcn_pwrite_kernel(const unsigned short* __restrict__ kbt,
                        const float* __restrict__ qk, const float* __restrict__ k8l,
                        const float* __restrict__ mpart, const float* __restrict__ lpart,
                        unsigned short* __restrict__ Pws, int phase)
{
    // steady: Kt[2][32][72] @0 | k8t[2][32] @9216 | Pt[128][56] @9472 | mjs @23808 | iljs @24320
    // transient: Qt[2][128][72] @0..36864 (dead before mjs/Kt first written)
    __shared__ __align__(16) unsigned char smem[36864];
    unsigned short* KtP   = (unsigned short*)smem;
    float*          k8tP  = (float*)(smem + 9216);
    unsigned short* PtP   = (unsigned short*)(smem + 9472);
    float*          mjsP  = (float*)(smem + 23808);
    float*          iljsP = (float*)(smem + 24320);
    unsigned short* QtP   = (unsigned short*)smem;

    const int tid  = threadIdx.x;
    const int w    = tid >> 6;
    const int lane = tid & 63;
    const int g    = lane >> 4;
    const int lr   = lane & 15;

    const int bb = blockIdx.y;            // 0..1 slot
    const int b  = 2 * phase + bb;
    const int jt = blockIdx.x >> 4, kc = blockIdx.x & 15;
    const int jbase = jt * 128;

    // Q prologue (identical to fused)
#pragma unroll
    for (int it = 0; it < 8; ++it) {
        int idx = tid + 512 * it;
        int j = idx & 127, cp = idx >> 7;
        int jg = jbase + j;
        float q0 = 0.f, q1 = 0.f;
        if (jg < HWDIM) {
            const float* qp = qk + ((size_t)b * CKDIM + 2 * cp) * HWDIM + jg;
            q0 = qp[0]; q1 = qp[HWDIM];
        }
        unsigned wh = cvtpk(q0, q1);
        float r0 = q0 - __uint_as_float(wh << 16);
        float r1 = q1 - __uint_as_float(wh & 0xFFFF0000u);
        *(unsigned*)&QtP[(0 * 128 + j) * 72 + 2 * cp] = wh;
        *(unsigned*)&QtP[(1 * 128 + j) * 72 + 2 * cp] = cvtpk(r0, r1);
    }
    __syncthreads();
    bf16x8 bqh[2], bql[2];
#pragma unroll
    for (int s = 0; s < 2; ++s) {
        bqh[s] = *(const bf16x8*)&QtP[(0 * 128 + w * 16 + lr) * 72 + 32 * s + 8 * g];
        bql[s] = *(const bf16x8*)&QtP[(1 * 128 + w * 16 + lr) * 72 + 32 * s + 8 * g];
    }
    __syncthreads();   // Qt dead

    const int s0 = (NSTEP * kc) / PCH, s1 = (NSTEP * (kc + 1)) / PCH;

    if (tid < 128) {   // merged stats
        int jg = jbase + tid;
        float m = 0.f, l = 0.f;
        if (jg < HWDIM) {
            m = -1e30f;
#pragma unroll
            for (int c = 0; c < NCHS; ++c) {
                float mc = mpart[(b * NCHS + c) * HWDIM + jg];
                float lc = lpart[(b * NCHS + c) * HWDIM + jg];
                float mn = fmaxf(m, mc);
                l = l * fexp2(m - mn) + lc * fexp2(mc - mn);
                m = mn;
            }
        }
        mjsP[tid]  = m;
        iljsP[tid] = (l > 0.f) ? 1.f / l : 0.f;
    }
    {
        int tt = tid >> 4, cq = tid & 15;
        uint2 k16 = *(const uint2*)(kbt + ((size_t)b * THW + s0 * 32 + tt) * CKDIM + 4 * cq);
        *(uint2*)&KtP[tt * 72 + 4 * cq] = k16;
        if (tid < 32) k8tP[tid] = k8l[b * THW + s0 * 32 + tid];
    }
    __syncthreads();

    const float mv_j = mjsP[w * 16 + lr], il_j = iljsP[w * 16 + lr];
    f32x4 zz = {0.f, 0.f, 0.f, 0.f};

    int cur = 0;
    for (int st = s0; st < s1; ++st) {
        const int t0 = st * 32;
        const bool nxt = (st + 1 < s1);
        uint2 k16;
        float k8next = 0.f;
        const int tt = tid >> 4, cq = tid & 15;
        if (nxt) {
            k16 = *(const uint2*)(kbt + ((size_t)b * THW + (st + 1) * 32 + tt) * CKDIM + 4 * cq);
            if (tid < 32) k8next = k8l[b * THW + (st + 1) * 32 + tid];
        }
        bf16x8 ak0[2], ak1[2];
#pragma unroll
        for (int s = 0; s < 2; ++s) {
            ak0[s] = *(const bf16x8*)&KtP[(cur * 32 + lr) * 72 + 32 * s + 8 * g];
            ak1[s] = *(const bf16x8*)&KtP[(cur * 32 + 16 + lr) * 72 + 32 * s + 8 * g];
        }
        f32x4 k80 = *(const f32x4*)&k8tP[cur * 32 + 4 * g];
        f32x4 k81 = *(const f32x4*)&k8tP[cur * 32 + 16 + 4 * g];
        f32x4 ab0 = zz, ab1 = zz;
#pragma unroll
        for (int s = 0; s < 2; ++s) {
            ab0 = __builtin_amdgcn_mfma_f32_16x16x32_bf16(ak0[s], bqh[s], ab0, 0, 0, 0);
            ab0 = __builtin_amdgcn_mfma_f32_16x16x32_bf16(ak0[s], bql[s], ab0, 0, 0, 0);
            ab1 = __builtin_amdgcn_mfma_f32_16x16x32_bf16(ak1[s], bqh[s], ab1, 0, 0, 0);
            ab1 = __builtin_amdgcn_mfma_f32_16x16x32_bf16(ak1[s], bql[s], ab1, 0, 0, 0);
        }
        if (nxt) {
            *(uint2*)&KtP[((cur ^ 1) * 32 + tt) * 72 + 4 * cq] = k16;
            if (tid < 32) k8tP[(cur ^ 1) * 32 + tid] = k8next;
        }
        float p0[4], p1[4];
#pragma unroll
        for (int r = 0; r < 4; ++r) {
            p0[r] = fexp2(fmaf(ab0[r], S2F, -k80[r]) - mv_j) * il_j;
            p1[r] = fexp2(fmaf(ab1[r], S2F, -k81[r]) - mv_j) * il_j;
        }
        __syncthreads();   // A: prev Pt consumers done
        {
            int jl = w * 16 + lr;
            *(uint2*)&PtP[jl * 56 + 4 * g]      = make_uint2(cvtpk(p0[0], p0[1]), cvtpk(p0[2], p0[3]));
            *(uint2*)&PtP[jl * 56 + 16 + 4 * g] = make_uint2(cvtpk(p1[0], p1[1]), cvtpk(p1[2], p1[3]));
        }
        __syncthreads();   // B: Pt ready
        {
            int jr = tid >> 2, qq = tid & 3;
            int jg = jbase + jr;
            if (jg < HWDIM)
                *(uint4*)(Pws + ((size_t)bb * HWDIM + jg) * THW + t0 + qq * 8) =
                    *(const uint4*)&PtP[jr * 56 + qq * 8];
        }
        cur ^= 1;
    }
}

// ---------------- GEMM: out[n][c][j] += sum_t V[n][c][t] * P[b][j][t]  (bf16 MFMA) ----------------
__global__ __launch_bounds__(512, 4)
void stcn_gemm_kernel(const unsigned short* __restrict__ mvb,
                      const unsigned short* __restrict__ Pws,
                      const int* __restrict__ bmap, float* __restrict__ out, int phase)
{
    __shared__ __align__(16) unsigned short Av[2][128 * 40];  // V tile [c][t32 pad40]
    __shared__ __align__(16) unsigned short Bv[2][128 * 40];  // P tile [j][t32 pad40]

    const int n = blockIdx.y;
    const int b = bmap[n];
    if ((b >> 1) != phase) return;
    const int bb = b & 1;
    const int x  = blockIdx.x;            // 2ks x 13jn x 4cm
    const int ks = x & 1;
    const int jn = (x >> 1) % NJT;
    const int cm = (x >> 1) / NJT;
    const int jbase = jn * 128, cb2 = cm * 128;

    const int tid = threadIdx.x, w = tid >> 6, lane = tid & 63, g = lane >> 4, lr = lane & 15;
    const int wc = w >> 2, wjj = w & 3;   // per-wave 64c x 32j
    const int row = tid >> 2, q = tid & 3;

    const unsigned short* vsrc = mvb + ((size_t)n * CVAL + cb2 + row) * THW + q * 8;
    const int jrow = jbase + row;
    const bool jok = jrow < HWDIM;
    const unsigned short* psrc = Pws + ((size_t)bb * HWDIM + (jok ? jrow : 0)) * THW + q * 8;

    const int s0 = (NSTEP * ks) / 2, s1 = (NSTEP * (ks + 1)) / 2;

    f32x4 zz = {0.f, 0.f, 0.f, 0.f};
    f32x4 acc[4][2];
#pragma unroll
    for (int i = 0; i < 4; ++i) { acc[i][0] = zz; acc[i][1] = zz; }

    {
        uint4 a = *(const uint4*)(vsrc + s0 * 32);
        uint4 p = jok ? *(const uint4*)(psrc + s0 * 32) : make_uint4(0, 0, 0, 0);
        *(uint4*)&Av[0][row * 40 + q * 8] = a;
        *(uint4*)&Bv[0][row * 40 + q * 8] = p;
    }
    __syncthreads();

    int cur = 0;
    for (int st = s0; st < s1; ++st) {
        const bool nxt = (st + 1 < s1);
        uint4 a, p;
        if (nxt) {
            a = *(const uint4*)(vsrc + (size_t)(st + 1) * 32);
            p = jok ? *(const uint4*)(psrc + (size_t)(st + 1) * 32) : make_uint4(0, 0, 0, 0);
        }
        bf16x8 av[4], bp[2];
#pragma unroll
        for (int cf = 0; cf < 4; ++cf)
            av[cf] = *(const bf16x8*)&Av[cur][(wc * 64 + cf * 16 + lr) * 40 + 8 * g];
#pragma unroll
        for (int jf = 0; jf < 2; ++jf)
            bp[jf] = *(const bf16x8*)&Bv[cur][(wjj * 32 + jf * 16 + lr) * 40 + 8 * g];
#pragma unroll
        for (int cf = 0; cf < 4; ++cf)
#pragma unroll
            for (int jf = 0; jf < 2; ++jf)
                acc[cf][jf] = __builtin_amdgcn_mfma_f32_16x16x32_bf16(av[cf], bp[jf], acc[cf][jf], 0, 0, 0);
        if (nxt) {
            *(uint4*)&Av[cur ^ 1][row * 40 + q * 8] = a;
            *(uint4*)&Bv[cur ^ 1][row * 40 + q * 8] = p;
        }
        __syncthreads();
        cur ^= 1;
    }

#pragma unroll
    for (int cf = 0; cf < 4; ++cf)
#pragma unroll
        for (int jf = 0; jf < 2; ++jf) {
            int jg = jbase + wjj * 32 + jf * 16 + lr;
            if (jg < HWDIM) {
                int c = cb2 + wc * 64 + cf * 16 + 4 * g;
                float* op = out + ((size_t)n * CVAL + c) * HWDIM + jg;
#pragma unroll
                for (int r = 0; r < 4; ++r)
                    atomicAdd(op + (size_t)r * HWDIM, acc[cf][jf][r]);
            }
        }
}

extern "C" void kernel_launch(void* const* d_in, const int* in_sizes, int n_in,
                              void* d_out, int out_size, void* d_ws, size_t ws_size,
                              hipStream_t stream) {
    (void)in_sizes; (void)n_in;
    const float* mk   = (const float*)d_in[0];
    const float* mv   = (const float*)d_in[1];
    const float* qkp  = (const float*)d_in[2];
    const int*   bmap = (const int*)d_in[3];
    float* out = (float*)d_out;

    // ws layout: k8l | mpart | lpart | mvb | kbt | Pws
    float* k8l   = (float*)d_ws;                          // NB*THW
    float* mpart = k8l + NB * THW;                        // NB*NCHS*HWDIM
    float* lpart = mpart + NB * NCHS * HWDIM;             // NB*NCHS*HWDIM
    unsigned short* mvb = (unsigned short*)(lpart + NB * NCHS * HWDIM);
    unsigned short* kbt = mvb + (size_t)NOBJ * CVAL * THW;
    unsigned short* Pws = kbt + (size_t)NB * THW * CKDIM;

    size_t base_bytes = (size_t)(NB * THW + 2 * NB * NCHS * HWDIM) * 4;
    size_t need_vb  = base_bytes + (size_t)NOBJ * CVAL * THW * 2;
    size_t need_kbt = need_vb + (size_t)NB * THW * CKDIM * 2;
    size_t need_P   = need_kbt + (size_t)2 * HWDIM * THW * 2;
    bool use_vb16 = (ws_size >= need_vb);    // proven true on this harness
    bool use_kbt  = (ws_size >= need_kbt);
    bool use_P    = (ws_size >= need_P);

    hipMemsetAsync(d_out, 0, (size_t)out_size * sizeof(float), stream);
    stcn_ksq_kernel<<<dim3((THW + 255) / 256, NB), 256, 0, stream>>>(mk, k8l);
    if (use_kbt)
        stcn_ktr_kernel<<<dim3((THW + 63) / 64, NB), 512, 0, stream>>>(mk, kbt);
    if (use_vb16) {
        size_t nthreads = (size_t)NOBJ * CVAL * THW / 8;
        stcn_vcvt_kernel<<<(unsigned)((nthreads + 255) / 256), 256, 0, stream>>>(mv, mvb);
    }

    // stats (all batches)
    if (use_kbt)
        stcn_aff_kernel<0, false, true><<<dim3(NJT * NCHS, NB), 512, 0, stream>>>(
            mk, kbt, qkp, k8l, mpart, lpart, nullptr, nullptr, nullptr, nullptr);
    else
        stcn_aff_kernel<0, false, false><<<dim3(NJT * NCHS, NB), 512, 0, stream>>>(
            mk, nullptr, qkp, k8l, mpart, lpart, nullptr, nullptr, nullptr, nullptr);

    if (use_P) {
        // phased: P for b in {0,1} then {2,3}; GEMM per phase (inactive objects early-exit)
        for (int p = 0; p < 2; ++p) {
            stcn_pwrite_kernel<<<dim3(NJT * PCH, 2), 512, 0, stream>>>(
                kbt, qkp, k8l, mpart, lpart, Pws, p);
            stcn_gemm_kernel<<<dim3(2 * NJT * 4, NOBJ), 512, 0, stream>>>(
                mvb, Pws, bmap, out, p);
        }
    } else {
        dim3 g1(NJT * NCHP * 2, NOBJ);
        if (use_vb16 && use_kbt)
            stcn_aff_kernel<1, true, true><<<g1, 512, 0, stream>>>(
                mk, kbt, qkp, k8l, mpart, lpart, nullptr, mvb, bmap, out);
        else if (use_vb16)
            stcn_aff_kernel<1, true, false><<<g1, 512, 0, stream>>>(
                mk, nullptr, qkp, k8l, mpart, lpart, nullptr, mvb, bmap, out);
        else
            stcn_aff_kernel<1, false, false><<<g1, 512, 0, stream>>>(
                mk, nullptr, qkp, k8l, mpart, lpart, mv, nullptr, bmap, out);
    }
}

// Round 6
// 554.083 us; speedup vs baseline: 2.4466x; 1.0308x over previous
//
#include <hip/hip_runtime.h>
#include <hip/hip_bf16.h>

// STCN read_memory: affinity softmax over THW + value readout.
#define CKDIM 64
#define THW   12960     // 8*30*54
#define HWDIM 1620      // 30*54
#define NOBJ  8
#define CVAL  512
#define NB    4
#define NSTEP 405       // THW / 32
#define NJT   13        // ceil(1620/128)
#define NCHS  8         // stats K-chunks
#define NCHP  4         // fallback fused-PV K-chunks
#define PCH   16        // P-write K-chunks
#define S2F   0.3606737602222409f   // 0.25 * log2(e)

using bf16x8 = __attribute__((ext_vector_type(8))) short;
using f32x4  = __attribute__((ext_vector_type(4))) float;

__device__ __forceinline__ unsigned cvtpk(float lo, float hi) {
    unsigned r;
    asm("v_cvt_pk_bf16_f32 %0, %1, %2" : "=v"(r) : "v"(lo), "v"(hi));
    return r;
}
__device__ __forceinline__ unsigned short bf_rne(float x) {
    unsigned u = __float_as_uint(x);
    u += 0x7FFFu + ((u >> 16) & 1u);
    return (unsigned short)(u >> 16);
}
__device__ __forceinline__ float fexp2(float x) {
#if __has_builtin(__builtin_amdgcn_exp2f)
    return __builtin_amdgcn_exp2f(x);
#else
    return __expf(x * 0.69314718055994531f);
#endif
}

// k8l[b][t] = (sum_c k^2)/8 * log2(e)
__global__ void stcn_ksq_kernel(const float* __restrict__ mk, float* __restrict__ k8l) {
    int t = blockIdx.x * 256 + threadIdx.x;
    if (t >= THW) return;
    int b = blockIdx.y;
    const float* p = mk + (size_t)b * CKDIM * THW + t;
    float s = 0.f;
#pragma unroll
    for (int c = 0; c < CKDIM; ++c) { float v = p[(size_t)c * THW]; s = fmaf(v, v, s); }
    k8l[b * THW + t] = s * (0.125f * 1.44269504088896341f);
}

// K [b][c][t] f32 -> kbt [b][t][c] bf16 (RNE)
__global__ __launch_bounds__(512)
void stcn_ktr_kernel(const float* __restrict__ mk, unsigned short* __restrict__ kbt) {
    __shared__ unsigned short L[64][72];
    const int tid = threadIdx.x, b = blockIdx.y, t0 = blockIdx.x * 64;
#pragma unroll
    for (int it = 0; it < 8; ++it) {
        int idx = tid + 512 * it;
        int tt = idx & 63, c = idx >> 6;
        int t = t0 + tt;
        float v = (t < THW) ? mk[((size_t)b * CKDIM + c) * THW + t] : 0.f;
        L[tt][c] = bf_rne(v);
    }
    __syncthreads();
    int tt = tid >> 3, cq = tid & 7;
    int t = t0 + tt;
    if (t < THW) {
        uint4 o = *(const uint4*)&L[tt][8 * cq];
        *(uint4*)(kbt + ((size_t)b * THW + t) * CKDIM + 8 * cq) = o;
    }
}

// V f32 -> bf16 (RNE)
__global__ void stcn_vcvt_kernel(const float* __restrict__ mv, unsigned short* __restrict__ mvb) {
    size_t i = ((size_t)blockIdx.x * 256 + threadIdx.x) * 8;
    if (i >= (size_t)NOBJ * CVAL * THW) return;
    float4 v0 = *(const float4*)(mv + i);
    float4 v1 = *(const float4*)(mv + i + 4);
    uint4 o;
    o.x = cvtpk(v0.x, v0.y); o.y = cvtpk(v0.z, v0.w);
    o.z = cvtpk(v1.x, v1.y); o.w = cvtpk(v1.z, v1.w);
    *(uint4*)(mvb + i) = o;
}

// ---------------- stats (MODE 0) + fused fallback PV (MODE 1) ----------------
template <int MODE, bool VB16, bool KB16>
__global__ __launch_bounds__(512, (MODE == 1) ? 4 : 1)
void stcn_aff_kernel(const float* __restrict__ mk, const unsigned short* __restrict__ kbt,
                     const float* __restrict__ qk, const float* __restrict__ k8l,
                     float* __restrict__ mpart, float* __restrict__ lpart,
                     const float* __restrict__ mv, const unsigned short* __restrict__ mvb,
                     const int* __restrict__ bmap, float* __restrict__ out)
{
    constexpr int SMEM_BYTES = (MODE == 0) ? 36864 : 45312;
    __shared__ __align__(16) unsigned char smem[SMEM_BYTES];
    unsigned short* KtP   = (unsigned short*)smem;
    float*          k8tP  = (float*)(smem + 9216);
    unsigned short* PtP   = (unsigned short*)(smem + 9472);
    unsigned short* VtP   = (unsigned short*)(smem + 23808);
    float*          mjsP  = (float*)(smem + 44288);
    float*          iljsP = (float*)(smem + 44800);
    unsigned short* QtP   = (unsigned short*)smem;

    const int tid  = threadIdx.x;
    const int w    = tid >> 6;
    const int lane = tid & 63;
    const int g    = lane >> 4;
    const int lr   = lane & 15;

    int b, n = 0, jt, kc, cb = 0;
    if (MODE == 0) { b = blockIdx.y; jt = blockIdx.x >> 3; kc = blockIdx.x & 7; }
    else {
        n = blockIdx.y; jt = blockIdx.x >> 3; kc = (blockIdx.x >> 1) & 3; cb = blockIdx.x & 1;
        b = bmap[n];
    }
    const int jbase = jt * 128;
    const int cbase = cb * 256;

#pragma unroll
    for (int it = 0; it < 8; ++it) {
        int idx = tid + 512 * it;
        int j = idx & 127, cp = idx >> 7;
        int jg = jbase + j;
        float q0 = 0.f, q1 = 0.f;
        if (jg < HWDIM) {
            const float* qp = qk + ((size_t)b * CKDIM + 2 * cp) * HWDIM + jg;
            q0 = qp[0]; q1 = qp[HWDIM];
        }
        unsigned wh = cvtpk(q0, q1);
        float r0 = q0 - __uint_as_float(wh << 16);
        float r1 = q1 - __uint_as_float(wh & 0xFFFF0000u);
        *(unsigned*)&QtP[(0 * 128 + j) * 72 + 2 * cp] = wh;
        *(unsigned*)&QtP[(1 * 128 + j) * 72 + 2 * cp] = cvtpk(r0, r1);
    }
    __syncthreads();
    bf16x8 bqh[2], bql[2];
#pragma unroll
    for (int s = 0; s < 2; ++s) {
        bqh[s] = *(const bf16x8*)&QtP[(0 * 128 + w * 16 + lr) * 72 + 32 * s + 8 * g];
        bql[s] = *(const bf16x8*)&QtP[(1 * 128 + w * 16 + lr) * 72 + 32 * s + 8 * g];
    }
    __syncthreads();

    auto stageK_loads = [&](int st, uint2& k16, float2* kvf) {
        if constexpr (KB16) {
            int tt = tid >> 4, cq = tid & 15;
            k16 = *(const uint2*)(kbt + ((size_t)b * THW + st * 32 + tt) * CKDIM + 4 * cq);
        } else {
#pragma unroll
            for (int it = 0; it < 2; ++it) {
                int idx = tid + 512 * it;
                int tt = idx & 31, cp = idx >> 5;
                const float* kp = mk + ((size_t)b * CKDIM + 2 * cp) * THW + st * 32 + tt;
                kvf[it].x = kp[0];
                kvf[it].y = kp[THW];
            }
        }
    };
    auto stageK_write = [&](int buf, uint2 k16, const float2* kvf) {
        if constexpr (KB16) {
            int tt = tid >> 4, cq = tid & 15;
            *(uint2*)&KtP[(buf * 32 + tt) * 72 + 4 * cq] = k16;
        } else {
#pragma unroll
            for (int it = 0; it < 2; ++it) {
                int idx = tid + 512 * it;
                int tt = idx & 31, cp = idx >> 5;
                *(unsigned*)&KtP[(buf * 32 + tt) * 72 + 2 * cp] = cvtpk(kvf[it].x, kvf[it].y);
            }
        }
    };

    int s0, s1;
    if (MODE == 0) { s0 = (NSTEP * kc) / NCHS; s1 = (NSTEP * (kc + 1)) / NCHS; }
    else           { s0 = (NSTEP * kc) / NCHP; s1 = (NSTEP * (kc + 1)) / NCHP; }

    if (MODE == 1 && tid < 128) {
        int jg = jbase + tid;
        float m = 0.f, l = 0.f;
        if (jg < HWDIM) {
            m = -1e30f;
#pragma unroll
            for (int c = 0; c < NCHS; ++c) {
                float mc = mpart[(b * NCHS + c) * HWDIM + jg];
                float lc = lpart[(b * NCHS + c) * HWDIM + jg];
                float mn = fmaxf(m, mc);
                l = l * fexp2(m - mn) + lc * fexp2(mc - mn);
                m = mn;
            }
        }
        mjsP[tid]  = m;
        iljsP[tid] = (l > 0.f) ? 1.f / l : 0.f;
    }
    {
        uint2 k16; float2 kvf[2];
        stageK_loads(s0, k16, kvf);
        stageK_write(0, k16, kvf);
        if (tid < 32) k8tP[tid] = k8l[b * THW + s0 * 32 + tid];
    }
    __syncthreads();

    float mv_j = 0.f, il_j = 0.f;
    if (MODE == 1) { mv_j = mjsP[w * 16 + lr]; il_j = iljsP[w * 16 + lr]; }

    float m_run = -1e30f, l_run = 0.f;
    f32x4 zz = {0.f, 0.f, 0.f, 0.f};
    f32x4 acc[4][4];
    if (MODE == 1)
#pragma unroll
        for (int i = 0; i < 4; ++i)
#pragma unroll
            for (int j = 0; j < 4; ++j) acc[i][j] = zz;

    const int wc = w >> 1, wj = w & 1;
    const int vc = tid >> 1, vth = tid & 1;

    int cur = 0;
    for (int st = s0; st < s1; ++st) {
        const int t0 = st * 32;
        const bool nxt = (st + 1 < s1);

        uint4 vw0 = {0,0,0,0}, vw1 = {0,0,0,0};
        if (MODE == 1) {
            if (VB16) {
                const unsigned short* vp = mvb + ((size_t)n * CVAL + cbase + vc) * THW + t0 + vth * 16;
                vw0 = *(const uint4*)vp;
                vw1 = *(const uint4*)(vp + 8);
            } else {
                const float* vp = mv + ((size_t)n * CVAL + cbase + vc) * THW + t0 + vth * 16;
                float4 f0 = *(const float4*)vp;
                float4 f1 = *(const float4*)(vp + 4);
                float4 f2 = *(const float4*)(vp + 8);
                float4 f3 = *(const float4*)(vp + 12);
                vw0 = make_uint4(cvtpk(f0.x,f0.y), cvtpk(f0.z,f0.w), cvtpk(f1.x,f1.y), cvtpk(f1.z,f1.w));
                vw1 = make_uint4(cvtpk(f2.x,f2.y), cvtpk(f2.z,f2.w), cvtpk(f3.x,f3.y), cvtpk(f3.z,f3.w));
            }
        }
        uint2 k16; float2 kvf[2];
        float k8next = 0.f;
        if (nxt) {
            stageK_loads(st + 1, k16, kvf);
            if (tid < 32) k8next = k8l[b * THW + (st + 1) * 32 + tid];
        }
        bf16x8 ak0[2], ak1[2];
#pragma unroll
        for (int s = 0; s < 2; ++s) {
            ak0[s] = *(const bf16x8*)&KtP[(cur * 32 + lr) * 72 + 32 * s + 8 * g];
            ak1[s] = *(const bf16x8*)&KtP[(cur * 32 + 16 + lr) * 72 + 32 * s + 8 * g];
        }
        f32x4 k80 = *(const f32x4*)&k8tP[cur * 32 + 4 * g];
        f32x4 k81 = *(const f32x4*)&k8tP[cur * 32 + 16 + 4 * g];
        f32x4 ab0 = zz, ab1 = zz;
#pragma unroll
        for (int s = 0; s < 2; ++s) {
            ab0 = __builtin_amdgcn_mfma_f32_16x16x32_bf16(ak0[s], bqh[s], ab0, 0, 0, 0);
            ab0 = __builtin_amdgcn_mfma_f32_16x16x32_bf16(ak0[s], bql[s], ab0, 0, 0, 0);
            ab1 = __builtin_amdgcn_mfma_f32_16x16x32_bf16(ak1[s], bqh[s], ab1, 0, 0, 0);
            ab1 = __builtin_amdgcn_mfma_f32_16x16x32_bf16(ak1[s], bql[s], ab1, 0, 0, 0);
        }
        if (nxt) {
            stageK_write(cur ^ 1, k16, kvf);
            if (tid < 32) k8tP[(cur ^ 1) * 32 + tid] = k8next;
        }

        if (MODE == 0) {
            float L0[4], L1[4], tmax = -1e30f;
#pragma unroll
            for (int r = 0; r < 4; ++r) {
                L0[r] = fmaf(ab0[r], S2F, -k80[r]); tmax = fmaxf(tmax, L0[r]);
                L1[r] = fmaf(ab1[r], S2F, -k81[r]); tmax = fmaxf(tmax, L1[r]);
            }
            float ps = 0.f;
#pragma unroll
            for (int r = 0; r < 4; ++r)
                ps += fexp2(L0[r] - tmax) + fexp2(L1[r] - tmax);
            float mn = fmaxf(m_run, tmax);
            l_run = l_run * fexp2(m_run - mn) + ps * fexp2(tmax - mn);
            m_run = mn;
            __syncthreads();
        } else {
            float p0[4], p1[4];
#pragma unroll
            for (int r = 0; r < 4; ++r) {
                p0[r] = fexp2(fmaf(ab0[r], S2F, -k80[r]) - mv_j) * il_j;
                p1[r] = fexp2(fmaf(ab1[r], S2F, -k81[r]) - mv_j) * il_j;
            }
            __syncthreads();
            {
                int jl = w * 16 + lr;
                *(uint2*)&PtP[jl * 56 + 4 * g]      = make_uint2(cvtpk(p0[0], p0[1]), cvtpk(p0[2], p0[3]));
                *(uint2*)&PtP[jl * 56 + 16 + 4 * g] = make_uint2(cvtpk(p1[0], p1[1]), cvtpk(p1[2], p1[3]));
                *(uint4*)&VtP[vc * 40 + vth * 16]     = vw0;
                *(uint4*)&VtP[vc * 40 + vth * 16 + 8] = vw1;
            }
            __syncthreads();
            bf16x8 bp[4];
#pragma unroll
            for (int jf = 0; jf < 4; ++jf)
                bp[jf] = *(const bf16x8*)&PtP[(wj * 64 + jf * 16 + lr) * 56 + 8 * g];
#pragma unroll
            for (int cf = 0; cf < 4; ++cf) {
                bf16x8 av = *(const bf16x8*)&VtP[(wc * 64 + cf * 16 + lr) * 40 + 8 * g];
#pragma unroll
                for (int jf = 0; jf < 4; ++jf)
                    acc[cf][jf] = __builtin_amdgcn_mfma_f32_16x16x32_bf16(av, bp[jf], acc[cf][jf], 0, 0, 0);
            }
        }
        cur ^= 1;
    }

    if (MODE == 0) {
#pragma unroll
        for (int off = 16; off < 64; off <<= 1) {
            float mo = __shfl_xor(m_run, off, 64);
            float lo = __shfl_xor(l_run, off, 64);
            float mn = fmaxf(m_run, mo);
            l_run = l_run * fexp2(m_run - mn) + lo * fexp2(mo - mn);
            m_run = mn;
        }
        int jg = jbase + w * 16 + lr;
        if (g == 0 && jg < HWDIM) {
            mpart[(b * NCHS + kc) * HWDIM + jg] = m_run;
            lpart[(b * NCHS + kc) * HWDIM + jg] = l_run;
        }
    } else {
#pragma unroll
        for (int cf = 0; cf < 4; ++cf) {
#pragma unroll
            for (int jf = 0; jf < 4; ++jf) {
                int jg = jbase + wj * 64 + jf * 16 + lr;
                if (jg < HWDIM) {
                    int c = cbase + wc * 64 + cf * 16 + 4 * g;
                    float* op = out + ((size_t)n * CVAL + c) * HWDIM + jg;
#pragma unroll
                    for (int r = 0; r < 4; ++r)
                        atomicAdd(op + (size_t)r * HWDIM, acc[cf][jf][r]);
                }
            }
        }
    }
}

// ---------------- P-write: softmax'd P (bf16) -> Pws[slot][j][t] ----------------
__global__ __launch_bounds__(512)
void stcn_pwrite_kernel(const unsigned short* __restrict__ kbt,
                        const float* __restrict__ qk, const float* __restrict__ k8l,
                        const float* __restrict__ mpart, const float* __restrict__ lpart,
                        unsigned short* __restrict__ Pws, int bbase)
{
    __shared__ __align__(16) unsigned char smem[36864];
    unsigned short* KtP   = (unsigned short*)smem;
    float*          k8tP  = (float*)(smem + 9216);
    unsigned short* PtP   = (unsigned short*)(smem + 9472);
    float*          mjsP  = (float*)(smem + 23808);
    float*          iljsP = (float*)(smem + 24320);
    unsigned short* QtP   = (unsigned short*)smem;

    const int tid  = threadIdx.x;
    const int w    = tid >> 6;
    const int lane = tid & 63;
    const int g    = lane >> 4;
    const int lr   = lane & 15;

    const int bb = blockIdx.y;            // Pws slot
    const int b  = bbase + bb;
    const int jt = blockIdx.x >> 4, kc = blockIdx.x & 15;
    const int jbase = jt * 128;

#pragma unroll
    for (int it = 0; it < 8; ++it) {
        int idx = tid + 512 * it;
        int j = idx & 127, cp = idx >> 7;
        int jg = jbase + j;
        float q0 = 0.f, q1 = 0.f;
        if (jg < HWDIM) {
            const float* qp = qk + ((size_t)b * CKDIM + 2 * cp) * HWDIM + jg;
            q0 = qp[0]; q1 = qp[HWDIM];
        }
        unsigned wh = cvtpk(q0, q1);
        float r0 = q0 - __uint_as_float(wh << 16);
        float r1 = q1 - __uint_as_float(wh & 0xFFFF0000u);
        *(unsigned*)&QtP[(0 * 128 + j) * 72 + 2 * cp] = wh;
        *(unsigned*)&QtP[(1 * 128 + j) * 72 + 2 * cp] = cvtpk(r0, r1);
    }
    __syncthreads();
    bf16x8 bqh[2], bql[2];
#pragma unroll
    for (int s = 0; s < 2; ++s) {
        bqh[s] = *(const bf16x8*)&QtP[(0 * 128 + w * 16 + lr) * 72 + 32 * s + 8 * g];
        bql[s] = *(const bf16x8*)&QtP[(1 * 128 + w * 16 + lr) * 72 + 32 * s + 8 * g];
    }
    __syncthreads();   // Qt dead

    const int s0 = (NSTEP * kc) / PCH, s1 = (NSTEP * (kc + 1)) / PCH;

    if (tid < 128) {
        int jg = jbase + tid;
        float m = 0.f, l = 0.f;
        if (jg < HWDIM) {
            m = -1e30f;
#pragma unroll
            for (int c = 0; c < NCHS; ++c) {
                float mc = mpart[(b * NCHS + c) * HWDIM + jg];
                float lc = lpart[(b * NCHS + c) * HWDIM + jg];
                float mn = fmaxf(m, mc);
                l = l * fexp2(m - mn) + lc * fexp2(mc - mn);
                m = mn;
            }
        }
        mjsP[tid]  = m;
        iljsP[tid] = (l > 0.f) ? 1.f / l : 0.f;
    }
    {
        int tt = tid >> 4, cq = tid & 15;
        uint2 k16 = *(const uint2*)(kbt + ((size_t)b * THW + s0 * 32 + tt) * CKDIM + 4 * cq);
        *(uint2*)&KtP[tt * 72 + 4 * cq] = k16;
        if (tid < 32) k8tP[tid] = k8l[b * THW + s0 * 32 + tid];
    }
    __syncthreads();

    const float mv_j = mjsP[w * 16 + lr], il_j = iljsP[w * 16 + lr];
    f32x4 zz = {0.f, 0.f, 0.f, 0.f};

    int cur = 0;
    for (int st = s0; st < s1; ++st) {
        const int t0 = st * 32;
        const bool nxt = (st + 1 < s1);
        uint2 k16;
        float k8next = 0.f;
        const int tt = tid >> 4, cq = tid & 15;
        if (nxt) {
            k16 = *(const uint2*)(kbt + ((size_t)b * THW + (st + 1) * 32 + tt) * CKDIM + 4 * cq);
            if (tid < 32) k8next = k8l[b * THW + (st + 1) * 32 + tid];
        }
        bf16x8 ak0[2], ak1[2];
#pragma unroll
        for (int s = 0; s < 2; ++s) {
            ak0[s] = *(const bf16x8*)&KtP[(cur * 32 + lr) * 72 + 32 * s + 8 * g];
            ak1[s] = *(const bf16x8*)&KtP[(cur * 32 + 16 + lr) * 72 + 32 * s + 8 * g];
        }
        f32x4 k80 = *(const f32x4*)&k8tP[cur * 32 + 4 * g];
        f32x4 k81 = *(const f32x4*)&k8tP[cur * 32 + 16 + 4 * g];
        f32x4 ab0 = zz, ab1 = zz;
#pragma unroll
        for (int s = 0; s < 2; ++s) {
            ab0 = __builtin_amdgcn_mfma_f32_16x16x32_bf16(ak0[s], bqh[s], ab0, 0, 0, 0);
            ab0 = __builtin_amdgcn_mfma_f32_16x16x32_bf16(ak0[s], bql[s], ab0, 0, 0, 0);
            ab1 = __builtin_amdgcn_mfma_f32_16x16x32_bf16(ak1[s], bqh[s], ab1, 0, 0, 0);
            ab1 = __builtin_amdgcn_mfma_f32_16x16x32_bf16(ak1[s], bql[s], ab1, 0, 0, 0);
        }
        if (nxt) {
            *(uint2*)&KtP[((cur ^ 1) * 32 + tt) * 72 + 4 * cq] = k16;
            if (tid < 32) k8tP[(cur ^ 1) * 32 + tid] = k8next;
        }
        float p0[4], p1[4];
#pragma unroll
        for (int r = 0; r < 4; ++r) {
            p0[r] = fexp2(fmaf(ab0[r], S2F, -k80[r]) - mv_j) * il_j;
            p1[r] = fexp2(fmaf(ab1[r], S2F, -k81[r]) - mv_j) * il_j;
        }
        __syncthreads();
        {
            int jl = w * 16 + lr;
            *(uint2*)&PtP[jl * 56 + 4 * g]      = make_uint2(cvtpk(p0[0], p0[1]), cvtpk(p0[2], p0[3]));
            *(uint2*)&PtP[jl * 56 + 16 + 4 * g] = make_uint2(cvtpk(p1[0], p1[1]), cvtpk(p1[2], p1[3]));
        }
        __syncthreads();
        {
            int jr = tid >> 2, qq = tid & 3;
            int jg = jbase + jr;
            if (jg < HWDIM)
                *(uint4*)(Pws + ((size_t)bb * HWDIM + jg) * THW + t0 + qq * 8) =
                    *(const uint4*)&PtP[jr * 56 + qq * 8];
        }
        cur ^= 1;
    }
}

// ---------------- GEMM v2: out[n][c][j] += sum_t V[n][c][t] * P[b][j][t] ----------------
// 256c x 128j tile, 8 waves of 64x64, BK=32, depth-2 reg prefetch, KSPLIT=4.
template <bool FULLP>
__global__ __launch_bounds__(512, 4)
void stcn_gemm2_kernel(const unsigned short* __restrict__ mvb,
                       const unsigned short* __restrict__ Pws,
                       const int* __restrict__ bmap, float* __restrict__ out, int phase)
{
    __shared__ __align__(16) unsigned short Av[2][256 * 40];  // V tile [c][t32 pad40]
    __shared__ __align__(16) unsigned short Bv[2][128 * 40];  // P tile [j][t32 pad40]

    const int n = blockIdx.y;
    const int b = bmap[n];
    int bslot;
    if constexpr (FULLP) { bslot = b; }
    else { if ((b >> 1) != phase) return; bslot = b & 1; }

    const int x    = blockIdx.x;          // 4ks x 13jn x 2cm = 104
    const int ks   = x & 3;
    const int rest = x >> 2;
    const int jn   = rest % NJT;
    const int cm   = rest / NJT;
    const int jbase = jn * 128, cbase = cm * 256;

    const int tid = threadIdx.x, w = tid >> 6, lane = tid & 63, g = lane >> 4, lr = lane & 15;
    const int wc = w >> 1, wj = w & 1;    // 4c x 2j wave grid, 64x64 each

    const int arow = tid >> 1, at = (tid & 1) * 16;  // A: 256 rows, 2 thr/row
    const int brow = tid >> 2, bt = (tid & 3) * 8;   // B: 128 rows, 4 thr/row
    const unsigned short* vsrc = mvb + ((size_t)n * CVAL + cbase + arow) * THW + at;
    const int jrow = jbase + brow;
    const bool jok = jrow < HWDIM;
    const unsigned short* psrc = Pws + ((size_t)bslot * HWDIM + (jok ? jrow : 0)) * THW + bt;

    const int s0 = (NSTEP * ks) / 4, s1 = (NSTEP * (ks + 1)) / 4;

    f32x4 zz = {0.f, 0.f, 0.f, 0.f};
    f32x4 acc[4][4];
#pragma unroll
    for (int i = 0; i < 4; ++i)
#pragma unroll
        for (int j = 0; j < 4; ++j) acc[i][j] = zz;

    const uint4 zq = make_uint4(0, 0, 0, 0);
    {   // stage s0 -> LDS[0]
        uint4 ta0 = *(const uint4*)(vsrc + (size_t)s0 * 32);
        uint4 ta1 = *(const uint4*)(vsrc + (size_t)s0 * 32 + 8);
        uint4 tb0 = jok ? *(const uint4*)(psrc + (size_t)s0 * 32) : zq;
        *(uint4*)&Av[0][arow * 40 + at]     = ta0;
        *(uint4*)&Av[0][arow * 40 + at + 8] = ta1;
        *(uint4*)&Bv[0][brow * 40 + bt]     = tb0;
    }
    // stage s0+1 -> regs (s1-s0 >= 101, always valid)
    uint4 nA0 = *(const uint4*)(vsrc + (size_t)(s0 + 1) * 32);
    uint4 nA1 = *(const uint4*)(vsrc + (size_t)(s0 + 1) * 32 + 8);
    uint4 nB0 = jok ? *(const uint4*)(psrc + (size_t)(s0 + 1) * 32) : zq;
    __syncthreads();

    int cur = 0;
    for (int st = s0; st < s1; ++st) {
        const bool h1 = (st + 1 < s1), h2 = (st + 2 < s1);
        uint4 fA0, fA1, fB0;
        if (h2) {   // issue loads 2 stages ahead
            fA0 = *(const uint4*)(vsrc + (size_t)(st + 2) * 32);
            fA1 = *(const uint4*)(vsrc + (size_t)(st + 2) * 32 + 8);
            fB0 = jok ? *(const uint4*)(psrc + (size_t)(st + 2) * 32) : zq;
        }
        bf16x8 bp[4];
#pragma unroll
        for (int jf = 0; jf < 4; ++jf)
            bp[jf] = *(const bf16x8*)&Bv[cur][(wj * 64 + jf * 16 + lr) * 40 + 8 * g];
        if (h1) {   // write stage st+1 into the other buffer
            *(uint4*)&Av[cur ^ 1][arow * 40 + at]     = nA0;
            *(uint4*)&Av[cur ^ 1][arow * 40 + at + 8] = nA1;
            *(uint4*)&Bv[cur ^ 1][brow * 40 + bt]     = nB0;
        }
#pragma unroll
        for (int cf = 0; cf < 4; ++cf) {
            bf16x8 av = *(const bf16x8*)&Av[cur][(wc * 64 + cf * 16 + lr) * 40 + 8 * g];
#pragma unroll
            for (int jf = 0; jf < 4; ++jf)
                acc[cf][jf] = __builtin_amdgcn_mfma_f32_16x16x32_bf16(av, bp[jf], acc[cf][jf], 0, 0, 0);
        }
        __syncthreads();
        if (h2) { nA0 = fA0; nA1 = fA1; nB0 = fB0; }
        cur ^= 1;
    }

#pragma unroll
    for (int cf = 0; cf < 4; ++cf)
#pragma unroll
        for (int jf = 0; jf < 4; ++jf) {
            int jg = jbase + wj * 64 + jf * 16 + lr;
            if (jg < HWDIM) {
                int c = cbase + wc * 64 + cf * 16 + 4 * g;
                float* op = out + ((size_t)n * CVAL + c) * HWDIM + jg;
#pragma unroll
                for (int r = 0; r < 4; ++r)
                    atomicAdd(op + (size_t)r * HWDIM, acc[cf][jf][r]);
            }
        }
}

extern "C" void kernel_launch(void* const* d_in, const int* in_sizes, int n_in,
                              void* d_out, int out_size, void* d_ws, size_t ws_size,
                              hipStream_t stream) {
    (void)in_sizes; (void)n_in;
    const float* mk   = (const float*)d_in[0];
    const float* mv   = (const float*)d_in[1];
    const float* qkp  = (const float*)d_in[2];
    const int*   bmap = (const int*)d_in[3];
    float* out = (float*)d_out;

    // ws layout: k8l | mpart | lpart | mvb | kbt | Pws
    float* k8l   = (float*)d_ws;
    float* mpart = k8l + NB * THW;
    float* lpart = mpart + NB * NCHS * HWDIM;
    unsigned short* mvb = (unsigned short*)(lpart + NB * NCHS * HWDIM);
    unsigned short* kbt = mvb + (size_t)NOBJ * CVAL * THW;
    unsigned short* Pws = kbt + (size_t)NB * THW * CKDIM;

    size_t base_bytes = (size_t)(NB * THW + 2 * NB * NCHS * HWDIM) * 4;
    size_t need_vb  = base_bytes + (size_t)NOBJ * CVAL * THW * 2;
    size_t need_kbt = need_vb + (size_t)NB * THW * CKDIM * 2;
    size_t need_P2  = need_kbt + (size_t)2 * HWDIM * THW * 2;
    size_t need_P4  = need_kbt + (size_t)4 * HWDIM * THW * 2;
    bool use_vb16 = (ws_size >= need_vb);
    bool use_kbt  = (ws_size >= need_kbt);
    bool use_P2   = (ws_size >= need_P2);
    bool use_P4   = (ws_size >= need_P4);

    hipMemsetAsync(d_out, 0, (size_t)out_size * sizeof(float), stream);
    stcn_ksq_kernel<<<dim3((THW + 255) / 256, NB), 256, 0, stream>>>(mk, k8l);
    if (use_kbt)
        stcn_ktr_kernel<<<dim3((THW + 63) / 64, NB), 512, 0, stream>>>(mk, kbt);
    if (use_vb16) {
        size_t nthreads = (size_t)NOBJ * CVAL * THW / 8;
        stcn_vcvt_kernel<<<(unsigned)((nthreads + 255) / 256), 256, 0, stream>>>(mv, mvb);
    }

    // stats (all batches)
    if (use_kbt)
        stcn_aff_kernel<0, false, true><<<dim3(NJT * NCHS, NB), 512, 0, stream>>>(
            mk, kbt, qkp, k8l, mpart, lpart, nullptr, nullptr, nullptr, nullptr);
    else
        stcn_aff_kernel<0, false, false><<<dim3(NJT * NCHS, NB), 512, 0, stream>>>(
            mk, nullptr, qkp, k8l, mpart, lpart, nullptr, nullptr, nullptr, nullptr);

    if (use_P4 && use_kbt) {
        // all 4 batches' P in one pass, one big GEMM
        stcn_pwrite_kernel<<<dim3(NJT * PCH, NB), 512, 0, stream>>>(
            kbt, qkp, k8l, mpart, lpart, Pws, 0);
        stcn_gemm2_kernel<true><<<dim3(104, NOBJ), 512, 0, stream>>>(
            mvb, Pws, bmap, out, 0);
    } else if (use_P2 && use_kbt) {
        for (int p = 0; p < 2; ++p) {
            stcn_pwrite_kernel<<<dim3(NJT * PCH, 2), 512, 0, stream>>>(
                kbt, qkp, k8l, mpart, lpart, Pws, 2 * p);
            stcn_gemm2_kernel<false><<<dim3(104, NOBJ), 512, 0, stream>>>(
                mvb, Pws, bmap, out, p);
        }
    } else {
        dim3 g1(NJT * NCHP * 2, NOBJ);
        if (use_vb16 && use_kbt)
            stcn_aff_kernel<1, true, true><<<g1, 512, 0, stream>>>(
                mk, kbt, qkp, k8l, mpart, lpart, nullptr, mvb, bmap, out);
        else if (use_vb16)
            stcn_aff_kernel<1, true, false><<<g1, 512, 0, stream>>>(
                mk, nullptr, qkp, k8l, mpart, lpart, nullptr, mvb, bmap, out);
        else
            stcn_aff_kernel<1, false, false><<<g1, 512, 0, stream>>>(
                mk, nullptr, qkp, k8l, mpart, lpart, mv, nullptr, bmap, out);
    }
}

// Round 7
// 553.230 us; speedup vs baseline: 2.4504x; 1.0015x over previous
//
#include <hip/hip_runtime.h>
#include <hip/hip_bf16.h>

// STCN read_memory: affinity softmax over THW + value readout.
#define CKDIM 64
#define THW   12960     // 8*30*54
#define HWDIM 1620      // 30*54
#define NOBJ  8
#define CVAL  512
#define NB    4
#define NSTEP 405       // THW / 32
#define NJT   13        // ceil(1620/128)
#define NCHS  8         // stats K-chunks
#define NCHP  4         // fallback fused-PV K-chunks
#define PCH   16        // P-write K-chunks
#define S2F   0.3606737602222409f   // 0.25 * log2(e)

#if defined(__has_builtin)
#if __has_builtin(__builtin_amdgcn_global_load_lds)
#define HAVE_GLL 1
#endif
#endif

using bf16x8 = __attribute__((ext_vector_type(8))) short;
using f32x4  = __attribute__((ext_vector_type(4))) float;

__device__ __forceinline__ unsigned cvtpk(float lo, float hi) {
    unsigned r;
    asm("v_cvt_pk_bf16_f32 %0, %1, %2" : "=v"(r) : "v"(lo), "v"(hi));
    return r;
}
__device__ __forceinline__ unsigned short bf_rne(float x) {
    unsigned u = __float_as_uint(x);
    u += 0x7FFFu + ((u >> 16) & 1u);
    return (unsigned short)(u >> 16);
}
__device__ __forceinline__ float fexp2(float x) {
#if __has_builtin(__builtin_amdgcn_exp2f)
    return __builtin_amdgcn_exp2f(x);
#else
    return __expf(x * 0.69314718055994531f);
#endif
}
#ifdef HAVE_GLL
__device__ __forceinline__ void gload16(const void* g, void* l) {
    __builtin_amdgcn_global_load_lds(
        (const __attribute__((address_space(1))) unsigned int*)g,
        (__attribute__((address_space(3))) unsigned int*)l, 16, 0, 0);
}
#endif

// k8l[b][t] = (sum_c k^2)/8 * log2(e)
__global__ void stcn_ksq_kernel(const float* __restrict__ mk, float* __restrict__ k8l) {
    int t = blockIdx.x * 256 + threadIdx.x;
    if (t >= THW) return;
    int b = blockIdx.y;
    const float* p = mk + (size_t)b * CKDIM * THW + t;
    float s = 0.f;
#pragma unroll
    for (int c = 0; c < CKDIM; ++c) { float v = p[(size_t)c * THW]; s = fmaf(v, v, s); }
    k8l[b * THW + t] = s * (0.125f * 1.44269504088896341f);
}

// K [b][c][t] f32 -> kbt [b][t][c] bf16 (RNE)
__global__ __launch_bounds__(512)
void stcn_ktr_kernel(const float* __restrict__ mk, unsigned short* __restrict__ kbt) {
    __shared__ unsigned short L[64][72];
    const int tid = threadIdx.x, b = blockIdx.y, t0 = blockIdx.x * 64;
#pragma unroll
    for (int it = 0; it < 8; ++it) {
        int idx = tid + 512 * it;
        int tt = idx & 63, c = idx >> 6;
        int t = t0 + tt;
        float v = (t < THW) ? mk[((size_t)b * CKDIM + c) * THW + t] : 0.f;
        L[tt][c] = bf_rne(v);
    }
    __syncthreads();
    int tt = tid >> 3, cq = tid & 7;
    int t = t0 + tt;
    if (t < THW) {
        uint4 o = *(const uint4*)&L[tt][8 * cq];
        *(uint4*)(kbt + ((size_t)b * THW + t) * CKDIM + 8 * cq) = o;
    }
}

// V f32 -> bf16 (RNE)
__global__ void stcn_vcvt_kernel(const float* __restrict__ mv, unsigned short* __restrict__ mvb) {
    size_t i = ((size_t)blockIdx.x * 256 + threadIdx.x) * 8;
    if (i >= (size_t)NOBJ * CVAL * THW) return;
    float4 v0 = *(const float4*)(mv + i);
    float4 v1 = *(const float4*)(mv + i + 4);
    uint4 o;
    o.x = cvtpk(v0.x, v0.y); o.y = cvtpk(v0.z, v0.w);
    o.z = cvtpk(v1.x, v1.y); o.w = cvtpk(v1.z, v1.w);
    *(uint4*)(mvb + i) = o;
}

// ---------------- stats (MODE 0) + fused fallback PV (MODE 1) ----------------
template <int MODE, bool VB16, bool KB16>
__global__ __launch_bounds__(512, (MODE == 1) ? 4 : 1)
void stcn_aff_kernel(const float* __restrict__ mk, const unsigned short* __restrict__ kbt,
                     const float* __restrict__ qk, const float* __restrict__ k8l,
                     float* __restrict__ mpart, float* __restrict__ lpart,
                     const float* __restrict__ mv, const unsigned short* __restrict__ mvb,
                     const int* __restrict__ bmap, float* __restrict__ out)
{
    constexpr int SMEM_BYTES = (MODE == 0) ? 36864 : 45312;
    __shared__ __align__(16) unsigned char smem[SMEM_BYTES];
    unsigned short* KtP   = (unsigned short*)smem;
    float*          k8tP  = (float*)(smem + 9216);
    unsigned short* PtP   = (unsigned short*)(smem + 9472);
    unsigned short* VtP   = (unsigned short*)(smem + 23808);
    float*          mjsP  = (float*)(smem + 44288);
    float*          iljsP = (float*)(smem + 44800);
    unsigned short* QtP   = (unsigned short*)smem;

    const int tid  = threadIdx.x;
    const int w    = tid >> 6;
    const int lane = tid & 63;
    const int g    = lane >> 4;
    const int lr   = lane & 15;

    int b, n = 0, jt, kc, cb = 0;
    if (MODE == 0) { b = blockIdx.y; jt = blockIdx.x >> 3; kc = blockIdx.x & 7; }
    else {
        n = blockIdx.y; jt = blockIdx.x >> 3; kc = (blockIdx.x >> 1) & 3; cb = blockIdx.x & 1;
        b = bmap[n];
    }
    const int jbase = jt * 128;
    const int cbase = cb * 256;

#pragma unroll
    for (int it = 0; it < 8; ++it) {
        int idx = tid + 512 * it;
        int j = idx & 127, cp = idx >> 7;
        int jg = jbase + j;
        float q0 = 0.f, q1 = 0.f;
        if (jg < HWDIM) {
            const float* qp = qk + ((size_t)b * CKDIM + 2 * cp) * HWDIM + jg;
            q0 = qp[0]; q1 = qp[HWDIM];
        }
        unsigned wh = cvtpk(q0, q1);
        float r0 = q0 - __uint_as_float(wh << 16);
        float r1 = q1 - __uint_as_float(wh & 0xFFFF0000u);
        *(unsigned*)&QtP[(0 * 128 + j) * 72 + 2 * cp] = wh;
        *(unsigned*)&QtP[(1 * 128 + j) * 72 + 2 * cp] = cvtpk(r0, r1);
    }
    __syncthreads();
    bf16x8 bqh[2], bql[2];
#pragma unroll
    for (int s = 0; s < 2; ++s) {
        bqh[s] = *(const bf16x8*)&QtP[(0 * 128 + w * 16 + lr) * 72 + 32 * s + 8 * g];
        bql[s] = *(const bf16x8*)&QtP[(1 * 128 + w * 16 + lr) * 72 + 32 * s + 8 * g];
    }
    __syncthreads();

    auto stageK_loads = [&](int st, uint2& k16, float2* kvf) {
        if constexpr (KB16) {
            int tt = tid >> 4, cq = tid & 15;
            k16 = *(const uint2*)(kbt + ((size_t)b * THW + st * 32 + tt) * CKDIM + 4 * cq);
        } else {
#pragma unroll
            for (int it = 0; it < 2; ++it) {
                int idx = tid + 512 * it;
                int tt = idx & 31, cp = idx >> 5;
                const float* kp = mk + ((size_t)b * CKDIM + 2 * cp) * THW + st * 32 + tt;
                kvf[it].x = kp[0];
                kvf[it].y = kp[THW];
            }
        }
    };
    auto stageK_write = [&](int buf, uint2 k16, const float2* kvf) {
        if constexpr (KB16) {
            int tt = tid >> 4, cq = tid & 15;
            *(uint2*)&KtP[(buf * 32 + tt) * 72 + 4 * cq] = k16;
        } else {
#pragma unroll
            for (int it = 0; it < 2; ++it) {
                int idx = tid + 512 * it;
                int tt = idx & 31, cp = idx >> 5;
                *(unsigned*)&KtP[(buf * 32 + tt) * 72 + 2 * cp] = cvtpk(kvf[it].x, kvf[it].y);
            }
        }
    };

    int s0, s1;
    if (MODE == 0) { s0 = (NSTEP * kc) / NCHS; s1 = (NSTEP * (kc + 1)) / NCHS; }
    else           { s0 = (NSTEP * kc) / NCHP; s1 = (NSTEP * (kc + 1)) / NCHP; }

    if (MODE == 1 && tid < 128) {
        int jg = jbase + tid;
        float m = 0.f, l = 0.f;
        if (jg < HWDIM) {
            m = -1e30f;
#pragma unroll
            for (int c = 0; c < NCHS; ++c) {
                float mc = mpart[(b * NCHS + c) * HWDIM + jg];
                float lc = lpart[(b * NCHS + c) * HWDIM + jg];
                float mn = fmaxf(m, mc);
                l = l * fexp2(m - mn) + lc * fexp2(mc - mn);
                m = mn;
            }
        }
        mjsP[tid]  = m;
        iljsP[tid] = (l > 0.f) ? 1.f / l : 0.f;
    }
    {
        uint2 k16; float2 kvf[2];
        stageK_loads(s0, k16, kvf);
        stageK_write(0, k16, kvf);
        if (tid < 32) k8tP[tid] = k8l[b * THW + s0 * 32 + tid];
    }
    __syncthreads();

    float mv_j = 0.f, il_j = 0.f;
    if (MODE == 1) { mv_j = mjsP[w * 16 + lr]; il_j = iljsP[w * 16 + lr]; }

    float m_run = -1e30f, l_run = 0.f;
    f32x4 zz = {0.f, 0.f, 0.f, 0.f};
    f32x4 acc[4][4];
    if (MODE == 1)
#pragma unroll
        for (int i = 0; i < 4; ++i)
#pragma unroll
            for (int j = 0; j < 4; ++j) acc[i][j] = zz;

    const int wc = w >> 1, wj = w & 1;
    const int vc = tid >> 1, vth = tid & 1;

    int cur = 0;
    for (int st = s0; st < s1; ++st) {
        const int t0 = st * 32;
        const bool nxt = (st + 1 < s1);

        uint4 vw0 = {0,0,0,0}, vw1 = {0,0,0,0};
        if (MODE == 1) {
            if (VB16) {
                const unsigned short* vp = mvb + ((size_t)n * CVAL + cbase + vc) * THW + t0 + vth * 16;
                vw0 = *(const uint4*)vp;
                vw1 = *(const uint4*)(vp + 8);
            } else {
                const float* vp = mv + ((size_t)n * CVAL + cbase + vc) * THW + t0 + vth * 16;
                float4 f0 = *(const float4*)vp;
                float4 f1 = *(const float4*)(vp + 4);
                float4 f2 = *(const float4*)(vp + 8);
                float4 f3 = *(const float4*)(vp + 12);
                vw0 = make_uint4(cvtpk(f0.x,f0.y), cvtpk(f0.z,f0.w), cvtpk(f1.x,f1.y), cvtpk(f1.z,f1.w));
                vw1 = make_uint4(cvtpk(f2.x,f2.y), cvtpk(f2.z,f2.w), cvtpk(f3.x,f3.y), cvtpk(f3.z,f3.w));
            }
        }
        uint2 k16; float2 kvf[2];
        float k8next = 0.f;
        if (nxt) {
            stageK_loads(st + 1, k16, kvf);
            if (tid < 32) k8next = k8l[b * THW + (st + 1) * 32 + tid];
        }
        bf16x8 ak0[2], ak1[2];
#pragma unroll
        for (int s = 0; s < 2; ++s) {
            ak0[s] = *(const bf16x8*)&KtP[(cur * 32 + lr) * 72 + 32 * s + 8 * g];
            ak1[s] = *(const bf16x8*)&KtP[(cur * 32 + 16 + lr) * 72 + 32 * s + 8 * g];
        }
        f32x4 k80 = *(const f32x4*)&k8tP[cur * 32 + 4 * g];
        f32x4 k81 = *(const f32x4*)&k8tP[cur * 32 + 16 + 4 * g];
        f32x4 ab0 = zz, ab1 = zz;
#pragma unroll
        for (int s = 0; s < 2; ++s) {
            ab0 = __builtin_amdgcn_mfma_f32_16x16x32_bf16(ak0[s], bqh[s], ab0, 0, 0, 0);
            ab0 = __builtin_amdgcn_mfma_f32_16x16x32_bf16(ak0[s], bql[s], ab0, 0, 0, 0);
            ab1 = __builtin_amdgcn_mfma_f32_16x16x32_bf16(ak1[s], bqh[s], ab1, 0, 0, 0);
            ab1 = __builtin_amdgcn_mfma_f32_16x16x32_bf16(ak1[s], bql[s], ab1, 0, 0, 0);
        }
        if (nxt) {
            stageK_write(cur ^ 1, k16, kvf);
            if (tid < 32) k8tP[(cur ^ 1) * 32 + tid] = k8next;
        }

        if (MODE == 0) {
            float L0[4], L1[4], tmax = -1e30f;
#pragma unroll
            for (int r = 0; r < 4; ++r) {
                L0[r] = fmaf(ab0[r], S2F, -k80[r]); tmax = fmaxf(tmax, L0[r]);
                L1[r] = fmaf(ab1[r], S2F, -k81[r]); tmax = fmaxf(tmax, L1[r]);
            }
            float ps = 0.f;
#pragma unroll
            for (int r = 0; r < 4; ++r)
                ps += fexp2(L0[r] - tmax) + fexp2(L1[r] - tmax);
            float mn = fmaxf(m_run, tmax);
            l_run = l_run * fexp2(m_run - mn) + ps * fexp2(tmax - mn);
            m_run = mn;
            __syncthreads();
        } else {
            float p0[4], p1[4];
#pragma unroll
            for (int r = 0; r < 4; ++r) {
                p0[r] = fexp2(fmaf(ab0[r], S2F, -k80[r]) - mv_j) * il_j;
                p1[r] = fexp2(fmaf(ab1[r], S2F, -k81[r]) - mv_j) * il_j;
            }
            __syncthreads();
            {
                int jl = w * 16 + lr;
                *(uint2*)&PtP[jl * 56 + 4 * g]      = make_uint2(cvtpk(p0[0], p0[1]), cvtpk(p0[2], p0[3]));
                *(uint2*)&PtP[jl * 56 + 16 + 4 * g] = make_uint2(cvtpk(p1[0], p1[1]), cvtpk(p1[2], p1[3]));
                *(uint4*)&VtP[vc * 40 + vth * 16]     = vw0;
                *(uint4*)&VtP[vc * 40 + vth * 16 + 8] = vw1;
            }
            __syncthreads();
            bf16x8 bp[4];
#pragma unroll
            for (int jf = 0; jf < 4; ++jf)
                bp[jf] = *(const bf16x8*)&PtP[(wj * 64 + jf * 16 + lr) * 56 + 8 * g];
#pragma unroll
            for (int cf = 0; cf < 4; ++cf) {
                bf16x8 av = *(const bf16x8*)&VtP[(wc * 64 + cf * 16 + lr) * 40 + 8 * g];
#pragma unroll
                for (int jf = 0; jf < 4; ++jf)
                    acc[cf][jf] = __builtin_amdgcn_mfma_f32_16x16x32_bf16(av, bp[jf], acc[cf][jf], 0, 0, 0);
            }
        }
        cur ^= 1;
    }

    if (MODE == 0) {
#pragma unroll
        for (int off = 16; off < 64; off <<= 1) {
            float mo = __shfl_xor(m_run, off, 64);
            float lo = __shfl_xor(l_run, off, 64);
            float mn = fmaxf(m_run, mo);
            l_run = l_run * fexp2(m_run - mn) + lo * fexp2(mo - mn);
            m_run = mn;
        }
        int jg = jbase + w * 16 + lr;
        if (g == 0 && jg < HWDIM) {
            mpart[(b * NCHS + kc) * HWDIM + jg] = m_run;
            lpart[(b * NCHS + kc) * HWDIM + jg] = l_run;
        }
    } else {
#pragma unroll
        for (int cf = 0; cf < 4; ++cf) {
#pragma unroll
            for (int jf = 0; jf < 4; ++jf) {
                int jg = jbase + wj * 64 + jf * 16 + lr;
                if (jg < HWDIM) {
                    int c = cbase + wc * 64 + cf * 16 + 4 * g;
                    float* op = out + ((size_t)n * CVAL + c) * HWDIM + jg;
#pragma unroll
                    for (int r = 0; r < 4; ++r)
                        atomicAdd(op + (size_t)r * HWDIM, acc[cf][jf][r]);
                }
            }
        }
    }
}

// ---------------- P-write: softmax'd P (bf16) -> Pws[slot][j][t] ----------------
__global__ __launch_bounds__(512)
void stcn_pwrite_kernel(const unsigned short* __restrict__ kbt,
                        const float* __restrict__ qk, const float* __restrict__ k8l,
                        const float* __restrict__ mpart, const float* __restrict__ lpart,
                        unsigned short* __restrict__ Pws, int bbase)
{
    __shared__ __align__(16) unsigned char smem[36864];
    unsigned short* KtP   = (unsigned short*)smem;
    float*          k8tP  = (float*)(smem + 9216);
    unsigned short* PtP   = (unsigned short*)(smem + 9472);
    float*          mjsP  = (float*)(smem + 23808);
    float*          iljsP = (float*)(smem + 24320);
    unsigned short* QtP   = (unsigned short*)smem;

    const int tid  = threadIdx.x;
    const int w    = tid >> 6;
    const int lane = tid & 63;
    const int g    = lane >> 4;
    const int lr   = lane & 15;

    const int bb = blockIdx.y;            // Pws slot
    const int b  = bbase + bb;
    const int jt = blockIdx.x >> 4, kc = blockIdx.x & 15;
    const int jbase = jt * 128;

#pragma unroll
    for (int it = 0; it < 8; ++it) {
        int idx = tid + 512 * it;
        int j = idx & 127, cp = idx >> 7;
        int jg = jbase + j;
        float q0 = 0.f, q1 = 0.f;
        if (jg < HWDIM) {
            const float* qp = qk + ((size_t)b * CKDIM + 2 * cp) * HWDIM + jg;
            q0 = qp[0]; q1 = qp[HWDIM];
        }
        unsigned wh = cvtpk(q0, q1);
        float r0 = q0 - __uint_as_float(wh << 16);
        float r1 = q1 - __uint_as_float(wh & 0xFFFF0000u);
        *(unsigned*)&QtP[(0 * 128 + j) * 72 + 2 * cp] = wh;
        *(unsigned*)&QtP[(1 * 128 + j) * 72 + 2 * cp] = cvtpk(r0, r1);
    }
    __syncthreads();
    bf16x8 bqh[2], bql[2];
#pragma unroll
    for (int s = 0; s < 2; ++s) {
        bqh[s] = *(const bf16x8*)&QtP[(0 * 128 + w * 16 + lr) * 72 + 32 * s + 8 * g];
        bql[s] = *(const bf16x8*)&QtP[(1 * 128 + w * 16 + lr) * 72 + 32 * s + 8 * g];
    }
    __syncthreads();   // Qt dead

    const int s0 = (NSTEP * kc) / PCH, s1 = (NSTEP * (kc + 1)) / PCH;

    if (tid < 128) {
        int jg = jbase + tid;
        float m = 0.f, l = 0.f;
        if (jg < HWDIM) {
            m = -1e30f;
#pragma unroll
            for (int c = 0; c < NCHS; ++c) {
                float mc = mpart[(b * NCHS + c) * HWDIM + jg];
                float lc = lpart[(b * NCHS + c) * HWDIM + jg];
                float mn = fmaxf(m, mc);
                l = l * fexp2(m - mn) + lc * fexp2(mc - mn);
                m = mn;
            }
        }
        mjsP[tid]  = m;
        iljsP[tid] = (l > 0.f) ? 1.f / l : 0.f;
    }
    {
        int tt = tid >> 4, cq = tid & 15;
        uint2 k16 = *(const uint2*)(kbt + ((size_t)b * THW + s0 * 32 + tt) * CKDIM + 4 * cq);
        *(uint2*)&KtP[tt * 72 + 4 * cq] = k16;
        if (tid < 32) k8tP[tid] = k8l[b * THW + s0 * 32 + tid];
    }
    __syncthreads();

    const float mv_j = mjsP[w * 16 + lr], il_j = iljsP[w * 16 + lr];
    f32x4 zz = {0.f, 0.f, 0.f, 0.f};

    int cur = 0;
    for (int st = s0; st < s1; ++st) {
        const int t0 = st * 32;
        const bool nxt = (st + 1 < s1);
        uint2 k16;
        float k8next = 0.f;
        const int tt = tid >> 4, cq = tid & 15;
        if (nxt) {
            k16 = *(const uint2*)(kbt + ((size_t)b * THW + (st + 1) * 32 + tt) * CKDIM + 4 * cq);
            if (tid < 32) k8next = k8l[b * THW + (st + 1) * 32 + tid];
        }
        bf16x8 ak0[2], ak1[2];
#pragma unroll
        for (int s = 0; s < 2; ++s) {
            ak0[s] = *(const bf16x8*)&KtP[(cur * 32 + lr) * 72 + 32 * s + 8 * g];
            ak1[s] = *(const bf16x8*)&KtP[(cur * 32 + 16 + lr) * 72 + 32 * s + 8 * g];
        }
        f32x4 k80 = *(const f32x4*)&k8tP[cur * 32 + 4 * g];
        f32x4 k81 = *(const f32x4*)&k8tP[cur * 32 + 16 + 4 * g];
        f32x4 ab0 = zz, ab1 = zz;
#pragma unroll
        for (int s = 0; s < 2; ++s) {
            ab0 = __builtin_amdgcn_mfma_f32_16x16x32_bf16(ak0[s], bqh[s], ab0, 0, 0, 0);
            ab0 = __builtin_amdgcn_mfma_f32_16x16x32_bf16(ak0[s], bql[s], ab0, 0, 0, 0);
            ab1 = __builtin_amdgcn_mfma_f32_16x16x32_bf16(ak1[s], bqh[s], ab1, 0, 0, 0);
            ab1 = __builtin_amdgcn_mfma_f32_16x16x32_bf16(ak1[s], bql[s], ab1, 0, 0, 0);
        }
        if (nxt) {
            *(uint2*)&KtP[((cur ^ 1) * 32 + tt) * 72 + 4 * cq] = k16;
            if (tid < 32) k8tP[(cur ^ 1) * 32 + tid] = k8next;
        }
        float p0[4], p1[4];
#pragma unroll
        for (int r = 0; r < 4; ++r) {
            p0[r] = fexp2(fmaf(ab0[r], S2F, -k80[r]) - mv_j) * il_j;
            p1[r] = fexp2(fmaf(ab1[r], S2F, -k81[r]) - mv_j) * il_j;
        }
        __syncthreads();
        {
            int jl = w * 16 + lr;
            *(uint2*)&PtP[jl * 56 + 4 * g]      = make_uint2(cvtpk(p0[0], p0[1]), cvtpk(p0[2], p0[3]));
            *(uint2*)&PtP[jl * 56 + 16 + 4 * g] = make_uint2(cvtpk(p1[0], p1[1]), cvtpk(p1[2], p1[3]));
        }
        __syncthreads();
        {
            int jr = tid >> 2, qq = tid & 3;
            int jg = jbase + jr;
            if (jg < HWDIM)
                *(uint4*)(Pws + ((size_t)bb * HWDIM + jg) * THW + t0 + qq * 8) =
                    *(const uint4*)&PtP[jr * 56 + qq * 8];
        }
        cur ^= 1;
    }
}

// ---------------- GEMM v3 (m97-style): out[n][c][j] += sum_t V[n][c][t] * P[b][j][t] ----------------
// 128c x 128j tile, 4 waves of 64x64, BK=32, global_load_lds dbuf, slot-XOR swizzle, KSPLIT=2.
template <bool FULLP>
__global__ __launch_bounds__(256, 4)
void stcn_gemm3_kernel(const unsigned short* __restrict__ mvb,
                       const unsigned short* __restrict__ Pws,
                       const int* __restrict__ bmap, float* __restrict__ out, int phase)
{
    // linear LDS tiles [128 rows][32 t] bf16; physical slot p holds logical t-slot p ^ ((row>>1)&3)
    __shared__ __align__(16) unsigned short Av[2][128 * 32];
    __shared__ __align__(16) unsigned short Bv[2][128 * 32];

    const int n = blockIdx.y;
    const int b = bmap[n];
    int bslot;
    if constexpr (FULLP) { bslot = b; }
    else { if ((b >> 1) != phase) return; bslot = b & 1; }

    const int x    = blockIdx.x;          // 2ks x 13jn x 4cm = 104
    const int ks   = x & 1;
    const int rest = x >> 1;
    const int jn   = rest % NJT;
    const int cm   = rest / NJT;
    const int jbase = jn * 128, cbase = cm * 128;

    const int tid = threadIdx.x;          // 256
    const int w = tid >> 6, lane = tid & 63, g = lane >> 4, lr = lane & 15;
    const int wc = w >> 1, wj = w & 1;    // 2x2 wave grid, 64x64 per wave

    // staging geometry: issue i covers LDS rows i*64 + (tid>>2); lane writes 16B linear
    const int srow = tid >> 2;
    const int tsw  = (((tid & 3) ^ ((tid >> 3) & 3)) << 3);   // pre-swizzled source t-offset
    // read-side swizzle constant: slot' = g ^ ((lr>>1)&3)
    const int gs8  = ((g ^ ((lr >> 1) & 3)) << 3);

    const int s0 = (NSTEP * ks) / 2, s1 = (NSTEP * (ks + 1)) / 2;

    const unsigned short* abase = mvb + ((size_t)n * CVAL + cbase) * THW;
    const unsigned short* bbase = Pws + (size_t)bslot * HWDIM * THW;
    int jr0 = jbase + srow;       if (jr0 >= HWDIM) jr0 = 0;
    int jr1 = jbase + 64 + srow;  if (jr1 >= HWDIM) jr1 = 0;
    const unsigned short* ga0 = abase + (size_t)(srow) * THW + tsw;
    const unsigned short* ga1 = abase + (size_t)(64 + srow) * THW + tsw;
    const unsigned short* gb0 = bbase + (size_t)jr0 * THW + tsw;
    const unsigned short* gb1 = bbase + (size_t)jr1 * THW + tsw;

    f32x4 zz = {0.f, 0.f, 0.f, 0.f};
    f32x4 acc[4][4];
#pragma unroll
    for (int i = 0; i < 4; ++i)
#pragma unroll
        for (int j = 0; j < 4; ++j) acc[i][j] = zz;

#ifdef HAVE_GLL
    auto stage = [&](int buf, int st) {
        const int t0 = st * 32;
        gload16(ga0 + t0, &Av[buf][0    + w * 512]);
        gload16(ga1 + t0, &Av[buf][2048 + w * 512]);
        gload16(gb0 + t0, &Bv[buf][0    + w * 512]);
        gload16(gb1 + t0, &Bv[buf][2048 + w * 512]);
    };
    stage(0, s0);
#else
    {
        const int t0 = s0 * 32;
        *(uint4*)&Av[0][tid * 8]        = *(const uint4*)(ga0 + t0);
        *(uint4*)&Av[0][2048 + tid * 8] = *(const uint4*)(ga1 + t0);
        *(uint4*)&Bv[0][tid * 8]        = *(const uint4*)(gb0 + t0);
        *(uint4*)&Bv[0][2048 + tid * 8] = *(const uint4*)(gb1 + t0);
    }
#endif
    __syncthreads();

    int cur = 0;
    for (int st = s0; st < s1; ++st) {
        const bool nxt = (st + 1 < s1);
#ifdef HAVE_GLL
        if (nxt) stage(cur ^ 1, st + 1);
#else
        uint4 ra0, ra1, rb0, rb1;
        if (nxt) {
            const int t0 = (st + 1) * 32;
            ra0 = *(const uint4*)(ga0 + t0);
            ra1 = *(const uint4*)(ga1 + t0);
            rb0 = *(const uint4*)(gb0 + t0);
            rb1 = *(const uint4*)(gb1 + t0);
        }
#endif
        bf16x8 av[4], bp[4];
#pragma unroll
        for (int cf = 0; cf < 4; ++cf)
            av[cf] = *(const bf16x8*)&Av[cur][(wc * 64 + cf * 16 + lr) * 32 + gs8];
#pragma unroll
        for (int jf = 0; jf < 4; ++jf)
            bp[jf] = *(const bf16x8*)&Bv[cur][(wj * 64 + jf * 16 + lr) * 32 + gs8];
#pragma unroll
        for (int cf = 0; cf < 4; ++cf)
#pragma unroll
            for (int jf = 0; jf < 4; ++jf)
                acc[cf][jf] = __builtin_amdgcn_mfma_f32_16x16x32_bf16(av[cf], bp[jf], acc[cf][jf], 0, 0, 0);
#ifndef HAVE_GLL
        if (nxt) {   // write-late: vmcnt wait overlaps the MFMAs above
            *(uint4*)&Av[cur ^ 1][tid * 8]        = ra0;
            *(uint4*)&Av[cur ^ 1][2048 + tid * 8] = ra1;
            *(uint4*)&Bv[cur ^ 1][tid * 8]        = rb0;
            *(uint4*)&Bv[cur ^ 1][2048 + tid * 8] = rb1;
        }
#endif
        __syncthreads();   // drains gload/ds ops; next iter's buffer is ready
        cur ^= 1;
    }

#pragma unroll
    for (int cf = 0; cf < 4; ++cf)
#pragma unroll
        for (int jf = 0; jf < 4; ++jf) {
            int jg = jbase + wj * 64 + jf * 16 + lr;
            if (jg < HWDIM) {
                int c = cbase + wc * 64 + cf * 16 + 4 * g;
                float* op = out + ((size_t)n * CVAL + c) * HWDIM + jg;
#pragma unroll
                for (int r = 0; r < 4; ++r)
                    atomicAdd(op + (size_t)r * HWDIM, acc[cf][jf][r]);
            }
        }
}

extern "C" void kernel_launch(void* const* d_in, const int* in_sizes, int n_in,
                              void* d_out, int out_size, void* d_ws, size_t ws_size,
                              hipStream_t stream) {
    (void)in_sizes; (void)n_in;
    const float* mk   = (const float*)d_in[0];
    const float* mv   = (const float*)d_in[1];
    const float* qkp  = (const float*)d_in[2];
    const int*   bmap = (const int*)d_in[3];
    float* out = (float*)d_out;

    // ws layout: k8l | mpart | lpart | mvb | kbt | Pws
    float* k8l   = (float*)d_ws;
    float* mpart = k8l + NB * THW;
    float* lpart = mpart + NB * NCHS * HWDIM;
    unsigned short* mvb = (unsigned short*)(lpart + NB * NCHS * HWDIM);
    unsigned short* kbt = mvb + (size_t)NOBJ * CVAL * THW;
    unsigned short* Pws = kbt + (size_t)NB * THW * CKDIM;

    size_t base_bytes = (size_t)(NB * THW + 2 * NB * NCHS * HWDIM) * 4;
    size_t need_vb  = base_bytes + (size_t)NOBJ * CVAL * THW * 2;
    size_t need_kbt = need_vb + (size_t)NB * THW * CKDIM * 2;
    size_t need_P2  = need_kbt + (size_t)2 * HWDIM * THW * 2;
    size_t need_P4  = need_kbt + (size_t)4 * HWDIM * THW * 2;
    bool use_vb16 = (ws_size >= need_vb);
    bool use_kbt  = (ws_size >= need_kbt);
    bool use_P2   = (ws_size >= need_P2);
    bool use_P4   = (ws_size >= need_P4);

    hipMemsetAsync(d_out, 0, (size_t)out_size * sizeof(float), stream);
    stcn_ksq_kernel<<<dim3((THW + 255) / 256, NB), 256, 0, stream>>>(mk, k8l);
    if (use_kbt)
        stcn_ktr_kernel<<<dim3((THW + 63) / 64, NB), 512, 0, stream>>>(mk, kbt);
    if (use_vb16) {
        size_t nthreads = (size_t)NOBJ * CVAL * THW / 8;
        stcn_vcvt_kernel<<<(unsigned)((nthreads + 255) / 256), 256, 0, stream>>>(mv, mvb);
    }

    // stats (all batches)
    if (use_kbt)
        stcn_aff_kernel<0, false, true><<<dim3(NJT * NCHS, NB), 512, 0, stream>>>(
            mk, kbt, qkp, k8l, mpart, lpart, nullptr, nullptr, nullptr, nullptr);
    else
        stcn_aff_kernel<0, false, false><<<dim3(NJT * NCHS, NB), 512, 0, stream>>>(
            mk, nullptr, qkp, k8l, mpart, lpart, nullptr, nullptr, nullptr, nullptr);

    if (use_P4 && use_kbt) {
        stcn_pwrite_kernel<<<dim3(NJT * PCH, NB), 512, 0, stream>>>(
            kbt, qkp, k8l, mpart, lpart, Pws, 0);
        stcn_gemm3_kernel<true><<<dim3(104, NOBJ), 256, 0, stream>>>(
            mvb, Pws, bmap, out, 0);
    } else if (use_P2 && use_kbt) {
        for (int p = 0; p < 2; ++p) {
            stcn_pwrite_kernel<<<dim3(NJT * PCH, 2), 512, 0, stream>>>(
                kbt, qkp, k8l, mpart, lpart, Pws, 2 * p);
            stcn_gemm3_kernel<false><<<dim3(104, NOBJ), 256, 0, stream>>>(
                mvb, Pws, bmap, out, p);
        }
    } else {
        dim3 g1(NJT * NCHP * 2, NOBJ);
        if (use_vb16 && use_kbt)
            stcn_aff_kernel<1, true, true><<<g1, 512, 0, stream>>>(
                mk, kbt, qkp, k8l, mpart, lpart, nullptr, mvb, bmap, out);
        else if (use_vb16)
            stcn_aff_kernel<1, true, false><<<g1, 512, 0, stream>>>(
                mk, nullptr, qkp, k8l, mpart, lpart, nullptr, mvb, bmap, out);
        else
            stcn_aff_kernel<1, false, false><<<g1, 512, 0, stream>>>(
                mk, nullptr, qkp, k8l, mpart, lpart, mv, nullptr, bmap, out);
    }
}

// Round 8
// 526.042 us; speedup vs baseline: 2.5770x; 1.0517x over previous
//
#include <hip/hip_runtime.h>
#include <hip/hip_bf16.h>

// STCN read_memory: affinity softmax over THW + value readout.
#define CKDIM 64
#define THW   12960     // 8*30*54
#define HWDIM 1620      // 30*54
#define NOBJ  8
#define CVAL  512
#define NB    4
#define NSTEP 405       // THW / 32
#define NJT   13        // ceil(1620/128)
#define NCHS  8         // stats K-chunks
#define NCHP  4         // fallback fused-PV K-chunks
#define PCH   16        // P-write K-chunks
#define S2F   0.3606737602222409f   // 0.25 * log2(e)

#if defined(__has_builtin)
#if __has_builtin(__builtin_amdgcn_global_load_lds)
#define HAVE_GLL 1
#endif
#endif

using bf16x8 = __attribute__((ext_vector_type(8))) short;
using f32x4  = __attribute__((ext_vector_type(4))) float;

__device__ __forceinline__ unsigned cvtpk(float lo, float hi) {
    unsigned r;
    asm("v_cvt_pk_bf16_f32 %0, %1, %2" : "=v"(r) : "v"(lo), "v"(hi));
    return r;
}
__device__ __forceinline__ unsigned short bf_rne(float x) {
    unsigned u = __float_as_uint(x);
    u += 0x7FFFu + ((u >> 16) & 1u);
    return (unsigned short)(u >> 16);
}
__device__ __forceinline__ float fexp2(float x) {
#if __has_builtin(__builtin_amdgcn_exp2f)
    return __builtin_amdgcn_exp2f(x);
#else
    return __expf(x * 0.69314718055994531f);
#endif
}
#ifdef HAVE_GLL
__device__ __forceinline__ void gload16(const void* g, void* l) {
    __builtin_amdgcn_global_load_lds(
        (const __attribute__((address_space(1))) unsigned int*)g,
        (__attribute__((address_space(3))) unsigned int*)l, 16, 0, 0);
}
#endif

// k8l[b][t] = (sum_c k^2)/8 * log2(e)  (fallback path only; kbt path fuses this into ktr)
__global__ void stcn_ksq_kernel(const float* __restrict__ mk, float* __restrict__ k8l) {
    int t = blockIdx.x * 256 + threadIdx.x;
    if (t >= THW) return;
    int b = blockIdx.y;
    const float* p = mk + (size_t)b * CKDIM * THW + t;
    float s = 0.f;
#pragma unroll
    for (int c = 0; c < CKDIM; ++c) { float v = p[(size_t)c * THW]; s = fmaf(v, v, s); }
    k8l[b * THW + t] = s * (0.125f * 1.44269504088896341f);
}

// K [b][c][t] f32 -> kbt [b][t][c] bf16 (RNE), fused k8l = (sum_c k^2)/8*log2(e)
__global__ __launch_bounds__(512)
void stcn_ktr_kernel(const float* __restrict__ mk, unsigned short* __restrict__ kbt,
                     float* __restrict__ k8l) {
    __shared__ unsigned short L[64][72];
    __shared__ float S[64][8];
    const int tid = threadIdx.x, b = blockIdx.y, t0 = blockIdx.x * 64;
    const int tt = tid & 63;
    float a2 = 0.f;
#pragma unroll
    for (int it = 0; it < 8; ++it) {
        int idx = tid + 512 * it;
        int c = idx >> 6;                 // tt = idx & 63 == tid & 63 (constant per thread)
        int t = t0 + tt;
        float v = (t < THW) ? mk[((size_t)b * CKDIM + c) * THW + t] : 0.f;
        L[tt][c] = bf_rne(v);
        a2 = fmaf(v, v, a2);
    }
    S[tt][tid >> 6] = a2;
    __syncthreads();
    if (tid < 64) {
        float s = 0.f;
#pragma unroll
        for (int q = 0; q < 8; ++q) s += S[tid][q];
        int t = t0 + tid;
        if (t < THW) k8l[b * THW + t] = s * (0.125f * 1.44269504088896341f);
    }
    {
        int tr = tid >> 3, cq = tid & 7;
        int t = t0 + tr;
        if (t < THW) {
            uint4 o = *(const uint4*)&L[tr][8 * cq];
            *(uint4*)(kbt + ((size_t)b * THW + t) * CKDIM + 8 * cq) = o;
        }
    }
}

// V f32 -> bf16 (RNE)
__global__ void stcn_vcvt_kernel(const float* __restrict__ mv, unsigned short* __restrict__ mvb) {
    size_t i = ((size_t)blockIdx.x * 256 + threadIdx.x) * 8;
    if (i >= (size_t)NOBJ * CVAL * THW) return;
    float4 v0 = *(const float4*)(mv + i);
    float4 v1 = *(const float4*)(mv + i + 4);
    uint4 o;
    o.x = cvtpk(v0.x, v0.y); o.y = cvtpk(v0.z, v0.w);
    o.z = cvtpk(v1.x, v1.y); o.w = cvtpk(v1.z, v1.w);
    *(uint4*)(mvb + i) = o;
}

// ---------------- stats (MODE 0) + fused fallback PV (MODE 1) ----------------
template <int MODE, bool VB16, bool KB16>
__global__ __launch_bounds__(512, (MODE == 1) ? 4 : 1)
void stcn_aff_kernel(const float* __restrict__ mk, const unsigned short* __restrict__ kbt,
                     const float* __restrict__ qk, const float* __restrict__ k8l,
                     float* __restrict__ mpart, float* __restrict__ lpart,
                     const float* __restrict__ mv, const unsigned short* __restrict__ mvb,
                     const int* __restrict__ bmap, float* __restrict__ out)
{
    constexpr int SMEM_BYTES = (MODE == 0) ? 36864 : 45312;
    __shared__ __align__(16) unsigned char smem[SMEM_BYTES];
    unsigned short* KtP   = (unsigned short*)smem;
    float*          k8tP  = (float*)(smem + 9216);
    unsigned short* PtP   = (unsigned short*)(smem + 9472);
    unsigned short* VtP   = (unsigned short*)(smem + 23808);
    float*          mjsP  = (float*)(smem + 44288);
    float*          iljsP = (float*)(smem + 44800);
    unsigned short* QtP   = (unsigned short*)smem;

    const int tid  = threadIdx.x;
    const int w    = tid >> 6;
    const int lane = tid & 63;
    const int g    = lane >> 4;
    const int lr   = lane & 15;

    int b, n = 0, jt, kc, cb = 0;
    if (MODE == 0) { b = blockIdx.y; jt = blockIdx.x >> 3; kc = blockIdx.x & 7; }
    else {
        n = blockIdx.y; jt = blockIdx.x >> 3; kc = (blockIdx.x >> 1) & 3; cb = blockIdx.x & 1;
        b = bmap[n];
    }
    const int jbase = jt * 128;
    const int cbase = cb * 256;

#pragma unroll
    for (int it = 0; it < 8; ++it) {
        int idx = tid + 512 * it;
        int j = idx & 127, cp = idx >> 7;
        int jg = jbase + j;
        float q0 = 0.f, q1 = 0.f;
        if (jg < HWDIM) {
            const float* qp = qk + ((size_t)b * CKDIM + 2 * cp) * HWDIM + jg;
            q0 = qp[0]; q1 = qp[HWDIM];
        }
        unsigned wh = cvtpk(q0, q1);
        float r0 = q0 - __uint_as_float(wh << 16);
        float r1 = q1 - __uint_as_float(wh & 0xFFFF0000u);
        *(unsigned*)&QtP[(0 * 128 + j) * 72 + 2 * cp] = wh;
        *(unsigned*)&QtP[(1 * 128 + j) * 72 + 2 * cp] = cvtpk(r0, r1);
    }
    __syncthreads();
    bf16x8 bqh[2], bql[2];
#pragma unroll
    for (int s = 0; s < 2; ++s) {
        bqh[s] = *(const bf16x8*)&QtP[(0 * 128 + w * 16 + lr) * 72 + 32 * s + 8 * g];
        bql[s] = *(const bf16x8*)&QtP[(1 * 128 + w * 16 + lr) * 72 + 32 * s + 8 * g];
    }
    __syncthreads();

    auto stageK_loads = [&](int st, uint2& k16, float2* kvf) {
        if constexpr (KB16) {
            int tt = tid >> 4, cq = tid & 15;
            k16 = *(const uint2*)(kbt + ((size_t)b * THW + st * 32 + tt) * CKDIM + 4 * cq);
        } else {
#pragma unroll
            for (int it = 0; it < 2; ++it) {
                int idx = tid + 512 * it;
                int tt = idx & 31, cp = idx >> 5;
                const float* kp = mk + ((size_t)b * CKDIM + 2 * cp) * THW + st * 32 + tt;
                kvf[it].x = kp[0];
                kvf[it].y = kp[THW];
            }
        }
    };
    auto stageK_write = [&](int buf, uint2 k16, const float2* kvf) {
        if constexpr (KB16) {
            int tt = tid >> 4, cq = tid & 15;
            *(uint2*)&KtP[(buf * 32 + tt) * 72 + 4 * cq] = k16;
        } else {
#pragma unroll
            for (int it = 0; it < 2; ++it) {
                int idx = tid + 512 * it;
                int tt = idx & 31, cp = idx >> 5;
                *(unsigned*)&KtP[(buf * 32 + tt) * 72 + 2 * cp] = cvtpk(kvf[it].x, kvf[it].y);
            }
        }
    };

    int s0, s1;
    if (MODE == 0) { s0 = (NSTEP * kc) / NCHS; s1 = (NSTEP * (kc + 1)) / NCHS; }
    else           { s0 = (NSTEP * kc) / NCHP; s1 = (NSTEP * (kc + 1)) / NCHP; }

    if (MODE == 1 && tid < 128) {
        int jg = jbase + tid;
        float m = 0.f, l = 0.f;
        if (jg < HWDIM) {
            m = -1e30f;
#pragma unroll
            for (int c = 0; c < NCHS; ++c) {
                float mc = mpart[(b * NCHS + c) * HWDIM + jg];
                float lc = lpart[(b * NCHS + c) * HWDIM + jg];
                float mn = fmaxf(m, mc);
                l = l * fexp2(m - mn) + lc * fexp2(mc - mn);
                m = mn;
            }
        }
        mjsP[tid]  = m;
        iljsP[tid] = (l > 0.f) ? 1.f / l : 0.f;
    }
    {
        uint2 k16; float2 kvf[2];
        stageK_loads(s0, k16, kvf);
        stageK_write(0, k16, kvf);
        if (tid < 32) k8tP[tid] = k8l[b * THW + s0 * 32 + tid];
    }
    __syncthreads();

    float mv_j = 0.f, il_j = 0.f;
    if (MODE == 1) { mv_j = mjsP[w * 16 + lr]; il_j = iljsP[w * 16 + lr]; }

    float m_run = -1e30f, l_run = 0.f;
    f32x4 zz = {0.f, 0.f, 0.f, 0.f};
    f32x4 acc[4][4];
    if (MODE == 1)
#pragma unroll
        for (int i = 0; i < 4; ++i)
#pragma unroll
            for (int j = 0; j < 4; ++j) acc[i][j] = zz;

    const int wc = w >> 1, wj = w & 1;
    const int vc = tid >> 1, vth = tid & 1;

    int cur = 0;
    for (int st = s0; st < s1; ++st) {
        const int t0 = st * 32;
        const bool nxt = (st + 1 < s1);

        uint4 vw0 = {0,0,0,0}, vw1 = {0,0,0,0};
        if (MODE == 1) {
            if (VB16) {
                const unsigned short* vp = mvb + ((size_t)n * CVAL + cbase + vc) * THW + t0 + vth * 16;
                vw0 = *(const uint4*)vp;
                vw1 = *(const uint4*)(vp + 8);
            } else {
                const float* vp = mv + ((size_t)n * CVAL + cbase + vc) * THW + t0 + vth * 16;
                float4 f0 = *(const float4*)vp;
                float4 f1 = *(const float4*)(vp + 4);
                float4 f2 = *(const float4*)(vp + 8);
                float4 f3 = *(const float4*)(vp + 12);
                vw0 = make_uint4(cvtpk(f0.x,f0.y), cvtpk(f0.z,f0.w), cvtpk(f1.x,f1.y), cvtpk(f1.z,f1.w));
                vw1 = make_uint4(cvtpk(f2.x,f2.y), cvtpk(f2.z,f2.w), cvtpk(f3.x,f3.y), cvtpk(f3.z,f3.w));
            }
        }
        uint2 k16; float2 kvf[2];
        float k8next = 0.f;
        if (nxt) {
            stageK_loads(st + 1, k16, kvf);
            if (tid < 32) k8next = k8l[b * THW + (st + 1) * 32 + tid];
        }
        bf16x8 ak0[2], ak1[2];
#pragma unroll
        for (int s = 0; s < 2; ++s) {
            ak0[s] = *(const bf16x8*)&KtP[(cur * 32 + lr) * 72 + 32 * s + 8 * g];
            ak1[s] = *(const bf16x8*)&KtP[(cur * 32 + 16 + lr) * 72 + 32 * s + 8 * g];
        }
        f32x4 k80 = *(const f32x4*)&k8tP[cur * 32 + 4 * g];
        f32x4 k81 = *(const f32x4*)&k8tP[cur * 32 + 16 + 4 * g];
        f32x4 ab0 = zz, ab1 = zz;
#pragma unroll
        for (int s = 0; s < 2; ++s) {
            ab0 = __builtin_amdgcn_mfma_f32_16x16x32_bf16(ak0[s], bqh[s], ab0, 0, 0, 0);
            ab0 = __builtin_amdgcn_mfma_f32_16x16x32_bf16(ak0[s], bql[s], ab0, 0, 0, 0);
            ab1 = __builtin_amdgcn_mfma_f32_16x16x32_bf16(ak1[s], bqh[s], ab1, 0, 0, 0);
            ab1 = __builtin_amdgcn_mfma_f32_16x16x32_bf16(ak1[s], bql[s], ab1, 0, 0, 0);
        }
        if (nxt) {
            stageK_write(cur ^ 1, k16, kvf);
            if (tid < 32) k8tP[(cur ^ 1) * 32 + tid] = k8next;
        }

        if (MODE == 0) {
            float L0[4], L1[4], tmax = -1e30f;
#pragma unroll
            for (int r = 0; r < 4; ++r) {
                L0[r] = fmaf(ab0[r], S2F, -k80[r]); tmax = fmaxf(tmax, L0[r]);
                L1[r] = fmaf(ab1[r], S2F, -k81[r]); tmax = fmaxf(tmax, L1[r]);
            }
            float ps = 0.f;
#pragma unroll
            for (int r = 0; r < 4; ++r)
                ps += fexp2(L0[r] - tmax) + fexp2(L1[r] - tmax);
            float mn = fmaxf(m_run, tmax);
            l_run = l_run * fexp2(m_run - mn) + ps * fexp2(tmax - mn);
            m_run = mn;
            __syncthreads();
        } else {
            float p0[4], p1[4];
#pragma unroll
            for (int r = 0; r < 4; ++r) {
                p0[r] = fexp2(fmaf(ab0[r], S2F, -k80[r]) - mv_j) * il_j;
                p1[r] = fexp2(fmaf(ab1[r], S2F, -k81[r]) - mv_j) * il_j;
            }
            __syncthreads();
            {
                int jl = w * 16 + lr;
                *(uint2*)&PtP[jl * 56 + 4 * g]      = make_uint2(cvtpk(p0[0], p0[1]), cvtpk(p0[2], p0[3]));
                *(uint2*)&PtP[jl * 56 + 16 + 4 * g] = make_uint2(cvtpk(p1[0], p1[1]), cvtpk(p1[2], p1[3]));
                *(uint4*)&VtP[vc * 40 + vth * 16]     = vw0;
                *(uint4*)&VtP[vc * 40 + vth * 16 + 8] = vw1;
            }
            __syncthreads();
            bf16x8 bp[4];
#pragma unroll
            for (int jf = 0; jf < 4; ++jf)
                bp[jf] = *(const bf16x8*)&PtP[(wj * 64 + jf * 16 + lr) * 56 + 8 * g];
#pragma unroll
            for (int cf = 0; cf < 4; ++cf) {
                bf16x8 av = *(const bf16x8*)&VtP[(wc * 64 + cf * 16 + lr) * 40 + 8 * g];
#pragma unroll
                for (int jf = 0; jf < 4; ++jf)
                    acc[cf][jf] = __builtin_amdgcn_mfma_f32_16x16x32_bf16(av, bp[jf], acc[cf][jf], 0, 0, 0);
            }
        }
        cur ^= 1;
    }

    if (MODE == 0) {
#pragma unroll
        for (int off = 16; off < 64; off <<= 1) {
            float mo = __shfl_xor(m_run, off, 64);
            float lo = __shfl_xor(l_run, off, 64);
            float mn = fmaxf(m_run, mo);
            l_run = l_run * fexp2(m_run - mn) + lo * fexp2(mo - mn);
            m_run = mn;
        }
        int jg = jbase + w * 16 + lr;
        if (g == 0 && jg < HWDIM) {
            mpart[(b * NCHS + kc) * HWDIM + jg] = m_run;
            lpart[(b * NCHS + kc) * HWDIM + jg] = l_run;
        }
    } else {
#pragma unroll
        for (int cf = 0; cf < 4; ++cf) {
#pragma unroll
            for (int jf = 0; jf < 4; ++jf) {
                int jg = jbase + wj * 64 + jf * 16 + lr;
                if (jg < HWDIM) {
                    int c = cbase + wc * 64 + cf * 16 + 4 * g;
                    float* op = out + ((size_t)n * CVAL + c) * HWDIM + jg;
#pragma unroll
                    for (int r = 0; r < 4; ++r)
                        atomicAdd(op + (size_t)r * HWDIM, acc[cf][jf][r]);
                }
            }
        }
    }
}

// ---------------- P-write: softmax'd P (bf16) -> Pws[slot][j][t] ----------------
__global__ __launch_bounds__(512)
void stcn_pwrite_kernel(const unsigned short* __restrict__ kbt,
                        const float* __restrict__ qk, const float* __restrict__ k8l,
                        const float* __restrict__ mpart, const float* __restrict__ lpart,
                        unsigned short* __restrict__ Pws, int bbase)
{
    __shared__ __align__(16) unsigned char smem[36864];
    unsigned short* KtP   = (unsigned short*)smem;
    float*          k8tP  = (float*)(smem + 9216);
    unsigned short* PtP   = (unsigned short*)(smem + 9472);
    float*          mjsP  = (float*)(smem + 23808);
    float*          iljsP = (float*)(smem + 24320);
    unsigned short* QtP   = (unsigned short*)smem;

    const int tid  = threadIdx.x;
    const int w    = tid >> 6;
    const int lane = tid & 63;
    const int g    = lane >> 4;
    const int lr   = lane & 15;

    const int bb = blockIdx.y;            // Pws slot
    const int b  = bbase + bb;
    const int jt = blockIdx.x >> 4, kc = blockIdx.x & 15;
    const int jbase = jt * 128;

#pragma unroll
    for (int it = 0; it < 8; ++it) {
        int idx = tid + 512 * it;
        int j = idx & 127, cp = idx >> 7;
        int jg = jbase + j;
        float q0 = 0.f, q1 = 0.f;
        if (jg < HWDIM) {
            const float* qp = qk + ((size_t)b * CKDIM + 2 * cp) * HWDIM + jg;
            q0 = qp[0]; q1 = qp[HWDIM];
        }
        unsigned wh = cvtpk(q0, q1);
        float r0 = q0 - __uint_as_float(wh << 16);
        float r1 = q1 - __uint_as_float(wh & 0xFFFF0000u);
        *(unsigned*)&QtP[(0 * 128 + j) * 72 + 2 * cp] = wh;
        *(unsigned*)&QtP[(1 * 128 + j) * 72 + 2 * cp] = cvtpk(r0, r1);
    }
    __syncthreads();
    bf16x8 bqh[2], bql[2];
#pragma unroll
    for (int s = 0; s < 2; ++s) {
        bqh[s] = *(const bf16x8*)&QtP[(0 * 128 + w * 16 + lr) * 72 + 32 * s + 8 * g];
        bql[s] = *(const bf16x8*)&QtP[(1 * 128 + w * 16 + lr) * 72 + 32 * s + 8 * g];
    }
    __syncthreads();   // Qt dead

    const int s0 = (NSTEP * kc) / PCH, s1 = (NSTEP * (kc + 1)) / PCH;

    if (tid < 128) {
        int jg = jbase + tid;
        float m = 0.f, l = 0.f;
        if (jg < HWDIM) {
            m = -1e30f;
#pragma unroll
            for (int c = 0; c < NCHS; ++c) {
                float mc = mpart[(b * NCHS + c) * HWDIM + jg];
                float lc = lpart[(b * NCHS + c) * HWDIM + jg];
                float mn = fmaxf(m, mc);
                l = l * fexp2(m - mn) + lc * fexp2(mc - mn);
                m = mn;
            }
        }
        mjsP[tid]  = m;
        iljsP[tid] = (l > 0.f) ? 1.f / l : 0.f;
    }
    {
        int tt = tid >> 4, cq = tid & 15;
        uint2 k16 = *(const uint2*)(kbt + ((size_t)b * THW + s0 * 32 + tt) * CKDIM + 4 * cq);
        *(uint2*)&KtP[tt * 72 + 4 * cq] = k16;
        if (tid < 32) k8tP[tid] = k8l[b * THW + s0 * 32 + tid];
    }
    __syncthreads();

    const float mv_j = mjsP[w * 16 + lr], il_j = iljsP[w * 16 + lr];
    f32x4 zz = {0.f, 0.f, 0.f, 0.f};

    int cur = 0;
    for (int st = s0; st < s1; ++st) {
        const int t0 = st * 32;
        const bool nxt = (st + 1 < s1);
        uint2 k16;
        float k8next = 0.f;
        const int tt = tid >> 4, cq = tid & 15;
        if (nxt) {
            k16 = *(const uint2*)(kbt + ((size_t)b * THW + (st + 1) * 32 + tt) * CKDIM + 4 * cq);
            if (tid < 32) k8next = k8l[b * THW + (st + 1) * 32 + tid];
        }
        bf16x8 ak0[2], ak1[2];
#pragma unroll
        for (int s = 0; s < 2; ++s) {
            ak0[s] = *(const bf16x8*)&KtP[(cur * 32 + lr) * 72 + 32 * s + 8 * g];
            ak1[s] = *(const bf16x8*)&KtP[(cur * 32 + 16 + lr) * 72 + 32 * s + 8 * g];
        }
        f32x4 k80 = *(const f32x4*)&k8tP[cur * 32 + 4 * g];
        f32x4 k81 = *(const f32x4*)&k8tP[cur * 32 + 16 + 4 * g];
        f32x4 ab0 = zz, ab1 = zz;
#pragma unroll
        for (int s = 0; s < 2; ++s) {
            ab0 = __builtin_amdgcn_mfma_f32_16x16x32_bf16(ak0[s], bqh[s], ab0, 0, 0, 0);
            ab0 = __builtin_amdgcn_mfma_f32_16x16x32_bf16(ak0[s], bql[s], ab0, 0, 0, 0);
            ab1 = __builtin_amdgcn_mfma_f32_16x16x32_bf16(ak1[s], bqh[s], ab1, 0, 0, 0);
            ab1 = __builtin_amdgcn_mfma_f32_16x16x32_bf16(ak1[s], bql[s], ab1, 0, 0, 0);
        }
        if (nxt) {
            *(uint2*)&KtP[((cur ^ 1) * 32 + tt) * 72 + 4 * cq] = k16;
            if (tid < 32) k8tP[(cur ^ 1) * 32 + tid] = k8next;
        }
        float p0[4], p1[4];
#pragma unroll
        for (int r = 0; r < 4; ++r) {
            p0[r] = fexp2(fmaf(ab0[r], S2F, -k80[r]) - mv_j) * il_j;
            p1[r] = fexp2(fmaf(ab1[r], S2F, -k81[r]) - mv_j) * il_j;
        }
        __syncthreads();
        {
            int jl = w * 16 + lr;
            *(uint2*)&PtP[jl * 56 + 4 * g]      = make_uint2(cvtpk(p0[0], p0[1]), cvtpk(p0[2], p0[3]));
            *(uint2*)&PtP[jl * 56 + 16 + 4 * g] = make_uint2(cvtpk(p1[0], p1[1]), cvtpk(p1[2], p1[3]));
        }
        __syncthreads();
        {
            int jr = tid >> 2, qq = tid & 3;
            int jg = jbase + jr;
            if (jg < HWDIM)
                *(uint4*)(Pws + ((size_t)bb * HWDIM + jg) * THW + t0 + qq * 8) =
                    *(const uint4*)&PtP[jr * 56 + qq * 8];
        }
        cur ^= 1;
    }
}

// ---------------- GEMM v4: out[n][c][j] += sum_t V[n][c][t] * P[b][j][t] ----------------
// 128c x 128j tile, 4 waves of 64x64, BK=32, global_load_lds dbuf, slot-XOR swizzle.
// FULLP: 1-D grid 1664 = 8n x 4cm x 13jn x 4ks, XCD-chunked bijective swizzle (one n per XCD).
template <bool FULLP>
__global__ __launch_bounds__(256, 4)
void stcn_gemm3_kernel(const unsigned short* __restrict__ mvb,
                       const unsigned short* __restrict__ Pws,
                       const int* __restrict__ bmap, float* __restrict__ out, int phase)
{
    __shared__ __align__(16) unsigned short Av[2][128 * 32];
    __shared__ __align__(16) unsigned short Bv[2][128 * 32];

    int n, cm, jn, ks, ksplit;
    if constexpr (FULLP) {
        int wg  = blockIdx.x;                      // 1664
        int vid = (wg & 7) * 208 + (wg >> 3);      // bijective: XCD gets contiguous 208 = one n
        n = vid / 208;
        int r  = vid % 208;
        cm = r / 52;                               // 52 = 13jn x 4ks; V slab stays L2-hot per cm
        int r2 = r % 52;
        jn = r2 >> 2;
        ks = r2 & 3;
        ksplit = 4;
    } else {
        n = blockIdx.y;
        const int x = blockIdx.x;                  // 2ks x 13jn x 4cm = 104
        ks = x & 1;
        const int rest = x >> 1;
        jn = rest % NJT;
        cm = rest / NJT;
        ksplit = 2;
    }
    const int b = bmap[n];
    int bslot;
    if constexpr (FULLP) { bslot = b; }
    else { if ((b >> 1) != phase) return; bslot = b & 1; }

    const int jbase = jn * 128, cbase = cm * 128;

    const int tid = threadIdx.x;          // 256
    const int w = tid >> 6, lane = tid & 63, g = lane >> 4, lr = lane & 15;
    const int wc = w >> 1, wj = w & 1;    // 2x2 wave grid, 64x64 per wave

    const int srow = tid >> 2;
    const int tsw  = (((tid & 3) ^ ((tid >> 3) & 3)) << 3);   // pre-swizzled source t-offset
    const int gs8  = ((g ^ ((lr >> 1) & 3)) << 3);            // read-side swizzle

    const int s0 = (NSTEP * ks) / ksplit, s1 = (NSTEP * (ks + 1)) / ksplit;

    const unsigned short* abase = mvb + ((size_t)n * CVAL + cbase) * THW;
    const unsigned short* bbase = Pws + (size_t)bslot * HWDIM * THW;
    int jr0 = jbase + srow;       if (jr0 >= HWDIM) jr0 = 0;
    int jr1 = jbase + 64 + srow;  if (jr1 >= HWDIM) jr1 = 0;
    const unsigned short* ga0 = abase + (size_t)(srow) * THW + tsw;
    const unsigned short* ga1 = abase + (size_t)(64 + srow) * THW + tsw;
    const unsigned short* gb0 = bbase + (size_t)jr0 * THW + tsw;
    const unsigned short* gb1 = bbase + (size_t)jr1 * THW + tsw;

    f32x4 zz = {0.f, 0.f, 0.f, 0.f};
    f32x4 acc[4][4];
#pragma unroll
    for (int i = 0; i < 4; ++i)
#pragma unroll
        for (int j = 0; j < 4; ++j) acc[i][j] = zz;

#ifdef HAVE_GLL
    auto stage = [&](int buf, int st) {
        const int t0 = st * 32;
        gload16(ga0 + t0, &Av[buf][0    + w * 512]);
        gload16(ga1 + t0, &Av[buf][2048 + w * 512]);
        gload16(gb0 + t0, &Bv[buf][0    + w * 512]);
        gload16(gb1 + t0, &Bv[buf][2048 + w * 512]);
    };
    stage(0, s0);
#else
    {
        const int t0 = s0 * 32;
        *(uint4*)&Av[0][tid * 8]        = *(const uint4*)(ga0 + t0);
        *(uint4*)&Av[0][2048 + tid * 8] = *(const uint4*)(ga1 + t0);
        *(uint4*)&Bv[0][tid * 8]        = *(const uint4*)(gb0 + t0);
        *(uint4*)&Bv[0][2048 + tid * 8] = *(const uint4*)(gb1 + t0);
    }
#endif
    __syncthreads();

    int cur = 0;
    for (int st = s0; st < s1; ++st) {
        const bool nxt = (st + 1 < s1);
#ifdef HAVE_GLL
        if (nxt) stage(cur ^ 1, st + 1);
#else
        uint4 ra0, ra1, rb0, rb1;
        if (nxt) {
            const int t0 = (st + 1) * 32;
            ra0 = *(const uint4*)(ga0 + t0);
            ra1 = *(const uint4*)(ga1 + t0);
            rb0 = *(const uint4*)(gb0 + t0);
            rb1 = *(const uint4*)(gb1 + t0);
        }
#endif
        bf16x8 av[4], bp[4];
#pragma unroll
        for (int cf = 0; cf < 4; ++cf)
            av[cf] = *(const bf16x8*)&Av[cur][(wc * 64 + cf * 16 + lr) * 32 + gs8];
#pragma unroll
        for (int jf = 0; jf < 4; ++jf)
            bp[jf] = *(const bf16x8*)&Bv[cur][(wj * 64 + jf * 16 + lr) * 32 + gs8];
#pragma unroll
        for (int cf = 0; cf < 4; ++cf)
#pragma unroll
            for (int jf = 0; jf < 4; ++jf)
                acc[cf][jf] = __builtin_amdgcn_mfma_f32_16x16x32_bf16(av[cf], bp[jf], acc[cf][jf], 0, 0, 0);
#ifndef HAVE_GLL
        if (nxt) {
            *(uint4*)&Av[cur ^ 1][tid * 8]        = ra0;
            *(uint4*)&Av[cur ^ 1][2048 + tid * 8] = ra1;
            *(uint4*)&Bv[cur ^ 1][tid * 8]        = rb0;
            *(uint4*)&Bv[cur ^ 1][2048 + tid * 8] = rb1;
        }
#endif
        __syncthreads();
        cur ^= 1;
    }

#pragma unroll
    for (int cf = 0; cf < 4; ++cf)
#pragma unroll
        for (int jf = 0; jf < 4; ++jf) {
            int jg = jbase + wj * 64 + jf * 16 + lr;
            if (jg < HWDIM) {
                int c = cbase + wc * 64 + cf * 16 + 4 * g;
                float* op = out + ((size_t)n * CVAL + c) * HWDIM + jg;
#pragma unroll
                for (int r = 0; r < 4; ++r)
                    atomicAdd(op + (size_t)r * HWDIM, acc[cf][jf][r]);
            }
        }
}

extern "C" void kernel_launch(void* const* d_in, const int* in_sizes, int n_in,
                              void* d_out, int out_size, void* d_ws, size_t ws_size,
                              hipStream_t stream) {
    (void)in_sizes; (void)n_in;
    const float* mk   = (const float*)d_in[0];
    const float* mv   = (const float*)d_in[1];
    const float* qkp  = (const float*)d_in[2];
    const int*   bmap = (const int*)d_in[3];
    float* out = (float*)d_out;

    // ws layout: k8l | mpart | lpart | mvb | kbt | Pws
    float* k8l   = (float*)d_ws;
    float* mpart = k8l + NB * THW;
    float* lpart = mpart + NB * NCHS * HWDIM;
    unsigned short* mvb = (unsigned short*)(lpart + NB * NCHS * HWDIM);
    unsigned short* kbt = mvb + (size_t)NOBJ * CVAL * THW;
    unsigned short* Pws = kbt + (size_t)NB * THW * CKDIM;

    size_t base_bytes = (size_t)(NB * THW + 2 * NB * NCHS * HWDIM) * 4;
    size_t need_vb  = base_bytes + (size_t)NOBJ * CVAL * THW * 2;
    size_t need_kbt = need_vb + (size_t)NB * THW * CKDIM * 2;
    size_t need_P2  = need_kbt + (size_t)2 * HWDIM * THW * 2;
    size_t need_P4  = need_kbt + (size_t)4 * HWDIM * THW * 2;
    bool use_vb16 = (ws_size >= need_vb);
    bool use_kbt  = (ws_size >= need_kbt);
    bool use_P2   = (ws_size >= need_P2);
    bool use_P4   = (ws_size >= need_P4);

    hipMemsetAsync(d_out, 0, (size_t)out_size * sizeof(float), stream);
    if (use_kbt)
        stcn_ktr_kernel<<<dim3((THW + 63) / 64, NB), 512, 0, stream>>>(mk, kbt, k8l);
    else
        stcn_ksq_kernel<<<dim3((THW + 255) / 256, NB), 256, 0, stream>>>(mk, k8l);
    if (use_vb16) {
        size_t nthreads = (size_t)NOBJ * CVAL * THW / 8;
        stcn_vcvt_kernel<<<(unsigned)((nthreads + 255) / 256), 256, 0, stream>>>(mv, mvb);
    }

    // stats (all batches)
    if (use_kbt)
        stcn_aff_kernel<0, false, true><<<dim3(NJT * NCHS, NB), 512, 0, stream>>>(
            mk, kbt, qkp, k8l, mpart, lpart, nullptr, nullptr, nullptr, nullptr);
    else
        stcn_aff_kernel<0, false, false><<<dim3(NJT * NCHS, NB), 512, 0, stream>>>(
            mk, nullptr, qkp, k8l, mpart, lpart, nullptr, nullptr, nullptr, nullptr);

    if (use_P4 && use_kbt) {
        stcn_pwrite_kernel<<<dim3(NJT * PCH, NB), 512, 0, stream>>>(
            kbt, qkp, k8l, mpart, lpart, Pws, 0);
        stcn_gemm3_kernel<true><<<dim3(1664), 256, 0, stream>>>(
            mvb, Pws, bmap, out, 0);
    } else if (use_P2 && use_kbt) {
        for (int p = 0; p < 2; ++p) {
            stcn_pwrite_kernel<<<dim3(NJT * PCH, 2), 512, 0, stream>>>(
                kbt, qkp, k8l, mpart, lpart, Pws, 2 * p);
            stcn_gemm3_kernel<false><<<dim3(104, NOBJ), 256, 0, stream>>>(
                mvb, Pws, bmap, out, p);
        }
    } else {
        dim3 g1(NJT * NCHP * 2, NOBJ);
        if (use_vb16 && use_kbt)
            stcn_aff_kernel<1, true, true><<<g1, 512, 0, stream>>>(
                mk, kbt, qkp, k8l, mpart, lpart, nullptr, mvb, bmap, out);
        else if (use_vb16)
            stcn_aff_kernel<1, true, false><<<g1, 512, 0, stream>>>(
                mk, nullptr, qkp, k8l, mpart, lpart, nullptr, mvb, bmap, out);
        else
            stcn_aff_kernel<1, false, false><<<g1, 512, 0, stream>>>(
                mk, nullptr, qkp, k8l, mpart, lpart, mv, nullptr, bmap, out);
    }
}